// Round 3
// baseline (2034.150 us; speedup 1.0000x reference)
//
#include <hip/hip_runtime.h>
#include <hip/hip_bf16.h>
#include <math.h>

#define N_NODES 20000
#define N_EDGES 640000
#define P_PATH 512
#define BIN_CAP 96     // max in-degree guard
#define CNT_STRIDE 32  // 1 counter per 128B line
#define GB 512         // mega grid blocks; all co-resident (LDS 53KB -> 3 blocks/CU, need 2)
#define NTILES 313     // ceil(20000/64)

typedef __attribute__((ext_vector_type(8))) short bf16x8;
typedef __attribute__((ext_vector_type(4))) float f32x4;

static __device__ __forceinline__ unsigned short f2bf(float f) {
    unsigned int b = __float_as_uint(f);
    unsigned int r = (b + 0x7fffu + ((b >> 16) & 1u)) >> 16;
    return (unsigned short)r;
}
static __device__ __forceinline__ float bfl(unsigned int u) { return __uint_as_float(u << 16); }
static __device__ __forceinline__ float bfh(unsigned int u) { return __uint_as_float(u & 0xffff0000u); }

static __device__ __forceinline__ void bf16_acc(float4& acc, uint2 u) {
    acc.x += bfl(u.x); acc.y += bfh(u.x);
    acc.z += bfl(u.y); acc.w += bfh(u.y);
}
static __device__ __forceinline__ float sigm(float x) { return 1.f / (1.f + expf(-x)); }

struct SMem {
    union {
        unsigned short X[64 * 128];                              // GIN bf16 tile (16 KB)
        float XL1[64 * 8];                                       // L1 fp32 tile
        struct { float z[512]; float z1[256]; float z2[64]; } fin;
    } u;
    unsigned short xs[64 * 256];  // path x-tile, persists attn pass1 -> pass2 (32 KB)
    float qs[3][256];
    float al[3][64];
    float wsum[4];
    int nodes[64];
};

// device-scope grid barrier (all GB blocks co-resident by construction)
static __device__ __forceinline__ void gridbar(int* bar, int* gen) {
    __syncthreads();
    __threadfence();
    if (threadIdx.x == 0) {
        int g = __hip_atomic_load(gen, __ATOMIC_ACQUIRE, __HIP_MEMORY_SCOPE_AGENT);
        int a = __hip_atomic_fetch_add(bar, 1, __ATOMIC_ACQ_REL, __HIP_MEMORY_SCOPE_AGENT);
        if (a == GB - 1) {
            __hip_atomic_store(bar, 0, __ATOMIC_RELAXED, __HIP_MEMORY_SCOPE_AGENT);
            __hip_atomic_fetch_add(gen, 1, __ATOMIC_RELEASE, __HIP_MEMORY_SCOPE_AGENT);
        } else {
            while (__hip_atomic_load(gen, __ATOMIC_ACQUIRE, __HIP_MEMORY_SCOPE_AGENT) == g)
                __builtin_amdgcn_s_sleep(1);
        }
    }
    __syncthreads();
    __threadfence();
}

// gather (self + neighbor sum) of a 64-node tile into LDS, bf16 out.
// TPN threads per node, UPT uint2 (4 bf16) per thread; TPN*UPT == DIM4IN.
template <int TPN, int UPT, int DIM4IN, int DIM4OUT>
static __device__ void gather_tile(const unsigned short* __restrict__ hb,
                                   const int* __restrict__ counts,
                                   const unsigned short* __restrict__ bins,
                                   int node0, unsigned short* X, int tid) {
    const uint2* hp = reinterpret_cast<const uint2*>(hb);
    uint2* Xp = reinterpret_cast<uint2*>(X);
    if (tid < 64 * TPN) {
        int nl = tid / TPN;
        int sub = tid - nl * TPN;
        int d4b = sub * UPT;
        int node = node0 + nl;
        float4 acc[UPT];
#pragma unroll
        for (int u = 0; u < UPT; ++u) acc[u] = {0.f, 0.f, 0.f, 0.f};
        if (node < N_NODES) {
            const uint2* selfp = hp + (size_t)node * DIM4IN + d4b;
#pragma unroll
            for (int u = 0; u < UPT; ++u) bf16_acc(acc[u], selfp[u]);
            int cnt = counts[node * CNT_STRIDE];
            if (cnt > BIN_CAP) cnt = BIN_CAP;
            const unsigned short* bp = bins + (size_t)node * BIN_CAP;
            int e = 0;
            for (; e + 2 <= cnt; e += 2) {
                const uint2* r0 = hp + (size_t)bp[e] * DIM4IN + d4b;
                const uint2* r1 = hp + (size_t)bp[e + 1] * DIM4IN + d4b;
                uint2 t0[UPT], t1[UPT];
#pragma unroll
                for (int u = 0; u < UPT; ++u) { t0[u] = r0[u]; t1[u] = r1[u]; }
#pragma unroll
                for (int u = 0; u < UPT; ++u) { bf16_acc(acc[u], t0[u]); bf16_acc(acc[u], t1[u]); }
            }
            if (e < cnt) {
                const uint2* r0 = hp + (size_t)bp[e] * DIM4IN + d4b;
#pragma unroll
                for (int u = 0; u < UPT; ++u) bf16_acc(acc[u], r0[u]);
            }
        }
#pragma unroll
        for (int u = 0; u < UPT; ++u) {
            uint2 o;
            o.x = (unsigned)f2bf(acc[u].x) | ((unsigned)f2bf(acc[u].y) << 16);
            o.y = (unsigned)f2bf(acc[u].z) | ((unsigned)f2bf(acc[u].w) << 16);
            Xp[nl * DIM4OUT + d4b + u] = o;
        }
    }
}

// MFMA from LDS X [64][K] bf16: out = relu(X @ Wb^T + bias), bf16 store.
template <int K, int N>
static __device__ void mfma_store_bf(const unsigned short* X,
                                     const unsigned short* __restrict__ Wb,
                                     const float* __restrict__ bias,
                                     unsigned short* __restrict__ out, int row0, int tid) {
    constexpr int NT = N / 16, KC = K / 32;
    int ln = tid & 63, wv = tid >> 6;
    int lr = ln & 15, lk = ln >> 4;
    f32x4 acc[NT];
#pragma unroll
    for (int t = 0; t < NT; ++t) acc[t] = (f32x4){0.f, 0.f, 0.f, 0.f};
#pragma unroll
    for (int kc = 0; kc < KC; ++kc) {
        bf16x8 a = *reinterpret_cast<const bf16x8*>(&X[(wv * 16 + lr) * K + kc * 32 + lk * 8]);
#pragma unroll
        for (int t = 0; t < NT; ++t) {
            bf16x8 b = *reinterpret_cast<const bf16x8*>(&Wb[(size_t)(t * 16 + lr) * K + kc * 32 + lk * 8]);
            acc[t] = __builtin_amdgcn_mfma_f32_16x16x32_bf16(a, b, acc[t], 0, 0, 0);
        }
    }
#pragma unroll
    for (int t = 0; t < NT; ++t) {
        float bj = bias[t * 16 + lr];
#pragma unroll
        for (int r = 0; r < 4; ++r) {
            int row = row0 + wv * 16 + lk * 4 + r;
            if (row < N_NODES)
                out[(size_t)row * N + t * 16 + lr] = f2bf(fmaxf(acc[t][r] + bj, 0.f));
        }
    }
}

// ---------------- init: zero counts+barrier, convert weights ----------------
__global__ __launch_bounds__(256) void init_all(const float* __restrict__ W2,
                                                const float* __restrict__ W3f,
                                                const float* __restrict__ W4f,
                                                const float* __restrict__ Wihf,
                                                int* __restrict__ counts, int* __restrict__ bar,
                                                unsigned short* __restrict__ Wb2p,
                                                unsigned short* __restrict__ Wb3,
                                                unsigned short* __restrict__ Wb4,
                                                unsigned short* __restrict__ Wihb) {
    int i = blockIdx.x * 256 + threadIdx.x;  // grid covers 786432
    if (i < N_NODES * CNT_STRIDE) counts[i] = 0;
    if (i < 2) bar[i] = 0;
    if (i < 2048) {
        int r = i >> 5, c = i & 31;
        Wb2p[i] = (c < 24) ? f2bf(W2[r * 24 + c]) : (unsigned short)0;
    }
    if (i < 8192) Wb3[i] = f2bf(W3f[i]);
    if (i < 32768) Wb4[i] = f2bf(W4f[i]);
    {
        int m = i >> 18;
        int rem = i & 262143;
        int j = rem >> 8, k = rem & 255;
        Wihb[i] = f2bf(Wihf[((size_t)m * 1024 + j) * 512 + 256 + k]);
    }
}

// ---------------- mega: everything else, 9 phases ----------------
__global__ __launch_bounds__(256, 2) void mega(
    const float* __restrict__ h0, const int* __restrict__ src, const int* __restrict__ dst,
    const int* __restrict__ path,
    const float* __restrict__ W1, const float* __restrict__ b1, const float* __restrict__ b2,
    const float* __restrict__ b3, const float* __restrict__ b4,
    const float* __restrict__ Wih, const float* __restrict__ Whh,
    const float* __restrict__ bih, const float* __restrict__ bhh,
    const float* __restrict__ Wg, const float* __restrict__ bg,
    const float* __restrict__ Wl1, const float* __restrict__ bl1,
    const float* __restrict__ Wl2, const float* __restrict__ bl2,
    const float* __restrict__ Wl3, const float* __restrict__ bl3,
    int* __restrict__ counts, unsigned short* __restrict__ bins,
    unsigned short* __restrict__ shA24, unsigned short* __restrict__ shB64,
    unsigned short* __restrict__ shA128, unsigned short* __restrict__ h4b,
    unsigned short* __restrict__ r0b, float* __restrict__ gates_all,
    float* __restrict__ cpart_all, float* __restrict__ xg,
    const unsigned short* __restrict__ Wb2p, const unsigned short* __restrict__ Wb3,
    const unsigned short* __restrict__ Wb4, const unsigned short* __restrict__ Wihb,
    int* __restrict__ bar, float* __restrict__ out) {
    __shared__ SMem sm;
    int tid = threadIdx.x, bx = blockIdx.x;
    int* gen = bar + 1;
    int ln = tid & 63, wv = tid >> 6;

    // ---- P1: fill_bins ----
    for (int e = bx * 256 + tid; e < N_EDGES; e += GB * 256) {
        int node = dst[e];
        int pos = atomicAdd(&counts[node * CNT_STRIDE], 1);
        if (pos < BIN_CAP) bins[(size_t)node * BIN_CAP + pos] = (unsigned short)src[e];
    }
    gridbar(bar, gen);

    // ---- P2: L1 (IN=8 fp32 gather + 8->24 matvec) ----
    if (bx < NTILES) {
        int node0 = bx * 64;
        float4* Xf = reinterpret_cast<float4*>(sm.u.XL1);
        const float4* hp = reinterpret_cast<const float4*>(h0);
        for (int it = tid; it < 128; it += 256) {
            int nl = it >> 1, d4 = it & 1;
            int node = node0 + nl;
            float4 a = {0.f, 0.f, 0.f, 0.f};
            if (node < N_NODES) {
                a = hp[(size_t)node * 2 + d4];  // self
                int cnt = counts[node * CNT_STRIDE];
                if (cnt > BIN_CAP) cnt = BIN_CAP;
                const unsigned short* bp = bins + (size_t)node * BIN_CAP;
                int e = 0;
                for (; e + 4 <= cnt; e += 4) {
                    float4 v0 = hp[(size_t)bp[e] * 2 + d4];
                    float4 v1 = hp[(size_t)bp[e + 1] * 2 + d4];
                    float4 v2 = hp[(size_t)bp[e + 2] * 2 + d4];
                    float4 v3 = hp[(size_t)bp[e + 3] * 2 + d4];
                    a.x += v0.x + v1.x + v2.x + v3.x;
                    a.y += v0.y + v1.y + v2.y + v3.y;
                    a.z += v0.z + v1.z + v2.z + v3.z;
                    a.w += v0.w + v1.w + v2.w + v3.w;
                }
                for (; e < cnt; ++e) {
                    float4 v = hp[(size_t)bp[e] * 2 + d4];
                    a.x += v.x; a.y += v.y; a.z += v.z; a.w += v.w;
                }
            }
            Xf[it] = a;
        }
        __syncthreads();
        int nl = tid >> 2, jg = tid & 3;
        int node = node0 + nl;
        if (node < N_NODES) {
            const float* Xa = sm.u.XL1 + nl * 8;
#pragma unroll
            for (int jj = 0; jj < 6; ++jj) {
                int j = jg * 6 + jj;
                float acc = b1[j];
#pragma unroll
                for (int k = 0; k < 8; ++k) acc += W1[j * 8 + k] * Xa[k];
                shA24[(size_t)node * 24 + j] = f2bf(fmaxf(acc, 0.f));
            }
        }
    }
    gridbar(bar, gen);

    // ---- P3: L2 (gather 24 -> pad 32, MFMA 32->64) ----
    if (bx < NTILES) {
        gather_tile<2, 3, 6, 8>(shA24, counts, bins, bx * 64, sm.u.X, tid);
        if (tid >= 128) {
            int it = tid - 128;
            int nl = it >> 1, dp = 6 + (it & 1);
            uint2 z; z.x = 0u; z.y = 0u;
            reinterpret_cast<uint2*>(sm.u.X)[nl * 8 + dp] = z;
        }
        __syncthreads();
        mfma_store_bf<32, 64>(sm.u.X, Wb2p, b2, shB64, bx * 64, tid);
    }
    gridbar(bar, gen);

    // ---- P4: L3 (MFMA 64->128) ----
    if (bx < NTILES) {
        gather_tile<4, 4, 16, 16>(shB64, counts, bins, bx * 64, sm.u.X, tid);
        __syncthreads();
        mfma_store_bf<64, 128>(sm.u.X, Wb3, b3, shA128, bx * 64, tid);
    }
    gridbar(bar, gen);

    // ---- P5: L4 (MFMA 128->256, bf16 h4) ----
    if (bx < NTILES) {
        gather_tile<4, 8, 32, 32>(shA128, counts, bins, bx * 64, sm.u.X, tid);
        __syncthreads();
        mfma_store_bf<128, 256>(sm.u.X, Wb4, b4, h4b, bx * 64, tid);
    }
    gridbar(bar, gen);

    // ---- P6: attn pass 1 (per path) + cpart ----
    {
        int p = bx;
#pragma unroll
        for (int m = 0; m < 3; ++m) {
            const float* bi = bih + (size_t)m * 1024;
            const float* bh = bhh + (size_t)m * 1024;
            float gi = bi[tid] + bh[tid];
            float gg = bi[512 + tid] + bh[512 + tid];
            float go = bi[768 + tid] + bh[768 + tid];
            sm.qs[m][tid] = sigm(go) * tanhf(sigm(gi) * tanhf(gg));  // hs1
        }
        if (tid < 64) sm.nodes[tid] = path[p * 64 + tid];
        __syncthreads();
        const uint2* h4p = reinterpret_cast<const uint2*>(h4b);
        for (int s = wv; s < 64; s += 4) {
            uint2 u = h4p[(size_t)sm.nodes[s] * 64 + ln];
            *reinterpret_cast<uint2*>(&sm.xs[s * 256 + ln * 4]) = u;
            float v0 = bfl(u.x), v1 = bfh(u.x), v2 = bfl(u.y), v3 = bfh(u.y);
            float d0 = v0 * sm.qs[0][ln * 4] + v1 * sm.qs[0][ln * 4 + 1] +
                       v2 * sm.qs[0][ln * 4 + 2] + v3 * sm.qs[0][ln * 4 + 3];
            float d1 = v0 * sm.qs[1][ln * 4] + v1 * sm.qs[1][ln * 4 + 1] +
                       v2 * sm.qs[1][ln * 4 + 2] + v3 * sm.qs[1][ln * 4 + 3];
            float d2 = v0 * sm.qs[2][ln * 4] + v1 * sm.qs[2][ln * 4 + 1] +
                       v2 * sm.qs[2][ln * 4 + 2] + v3 * sm.qs[2][ln * 4 + 3];
            for (int off = 32; off >= 1; off >>= 1) {
                d0 += __shfl_xor(d0, off, 64);
                d1 += __shfl_xor(d1, off, 64);
                d2 += __shfl_xor(d2, off, 64);
            }
            if (ln == 0) { sm.al[0][s] = d0; sm.al[1][s] = d1; sm.al[2][s] = d2; }
        }
        __syncthreads();
        if (wv < 3) {
            float v = sm.al[wv][ln];
            float mx = v;
            for (int off = 32; off >= 1; off >>= 1) mx = fmaxf(mx, __shfl_xor(mx, off, 64));
            float e = expf(v - mx);
            float s = e;
            for (int off = 32; off >= 1; off >>= 1) s += __shfl_xor(s, off, 64);
            sm.al[wv][ln] = e / s;
        }
        __syncthreads();
        float a0 = 0.f, a1 = 0.f, a2 = 0.f;
        for (int s = 0; s < 64; ++s) {
            float xv = bfl((unsigned)sm.xs[s * 256 + tid]);
            a0 += sm.al[0][s] * xv;
            a1 += sm.al[1][s] * xv;
            a2 += sm.al[2][s] * xv;
        }
        r0b[((size_t)0 * P_PATH + p) * 256 + tid] = f2bf(a0);
        r0b[((size_t)1 * P_PATH + p) * 256 + tid] = f2bf(a1);
        r0b[((size_t)2 * P_PATH + p) * 256 + tid] = f2bf(a2);
        // cpart: 6 outputs per block, wave-dots of length 256
#pragma unroll
        for (int rep = 0; rep < 2; ++rep) {
            int qi = wv + rep * 4;
            if (qi < 6) {
                int o = p * 6 + qi;
                int m = o >> 10, j = o & 1023;
                float4 wiv = reinterpret_cast<const float4*>(Wih + ((size_t)m * 1024 + j) * 512)[ln];
                float4 whv = reinterpret_cast<const float4*>(Whh + ((size_t)m * 1024 + j) * 256)[ln];
                float4 hv = *reinterpret_cast<const float4*>(&sm.qs[m][ln * 4]);
                float acc = hv.x * (wiv.x + whv.x) + hv.y * (wiv.y + whv.y) +
                            hv.z * (wiv.z + whv.z) + hv.w * (wiv.w + whv.w);
                for (int off = 32; off >= 1; off >>= 1) acc += __shfl_xor(acc, off, 64);
                if (ln == 0) cpart_all[o] = acc + bih[o] + bhh[o];
            }
        }
    }
    gridbar(bar, gen);

    // ---- P7: gates GEMM (96 blocks): gates = r0b @ Wihb^T + cpart ----
    if (bx < 96) {
        int m = bx >> 5;
        int r = bx & 31;
        int p0 = (r & 7) * 64;
        int j0 = (r >> 3) * 256;
        const unsigned short* A = r0b + (size_t)m * 512 * 256;
        const unsigned short* B = Wihb + (size_t)m * 1024 * 256 + (size_t)j0 * 256;
        const float* bias = cpart_all + m * 1024 + j0;
        float* og = gates_all + (size_t)m * 512 * 1024;
        int lr = ln & 15, lk = ln >> 4;
        int row0 = p0 + wv * 16;
        f32x4 acc[16];
#pragma unroll
        for (int t = 0; t < 16; ++t) acc[t] = (f32x4){0.f, 0.f, 0.f, 0.f};
#pragma unroll
        for (int kc = 0; kc < 8; ++kc) {
            bf16x8 a = *reinterpret_cast<const bf16x8*>(&A[(size_t)(row0 + lr) * 256 + kc * 32 + lk * 8]);
#pragma unroll
            for (int t = 0; t < 16; ++t) {
                bf16x8 b = *reinterpret_cast<const bf16x8*>(&B[(size_t)(t * 16 + lr) * 256 + kc * 32 + lk * 8]);
                acc[t] = __builtin_amdgcn_mfma_f32_16x16x32_bf16(a, b, acc[t], 0, 0, 0);
            }
        }
#pragma unroll
        for (int t = 0; t < 16; ++t) {
            float bj = bias[t * 16 + lr];
#pragma unroll
            for (int rr = 0; rr < 4; ++rr) {
                int row = row0 + lk * 4 + rr;
                og[(size_t)row * 1024 + j0 + t * 16 + lr] = acc[t][rr] + bj;
            }
        }
    }
    gridbar(bar, gen);

    // ---- P8: attn pass 2 (per path, xs still in LDS) ----
    {
        int p = bx;
#pragma unroll
        for (int m = 0; m < 3; ++m) {
            const float* bi = bih + (size_t)m * 1024;
            const float* bh = bhh + (size_t)m * 1024;
            float gi0 = bi[tid] + bh[tid];
            float gg0 = bi[512 + tid] + bh[512 + tid];
            float c0 = sigm(gi0) * tanhf(gg0);
            const float* g = gates_all + ((size_t)m * P_PATH + p) * 1024;
            float gi = g[tid], gf = g[256 + tid], gg = g[512 + tid], go = g[768 + tid];
            float c1 = sigm(gf) * c0 + sigm(gi) * tanhf(gg);
            sm.qs[m][tid] = sigm(go) * tanhf(c1);  // hs2 = q2
        }
        __syncthreads();
        for (int s = wv; s < 64; s += 4) {
            uint2 u = *reinterpret_cast<const uint2*>(&sm.xs[s * 256 + ln * 4]);
            float v0 = bfl(u.x), v1 = bfh(u.x), v2 = bfl(u.y), v3 = bfh(u.y);
            float d0 = v0 * sm.qs[0][ln * 4] + v1 * sm.qs[0][ln * 4 + 1] +
                       v2 * sm.qs[0][ln * 4 + 2] + v3 * sm.qs[0][ln * 4 + 3];
            float d1 = v0 * sm.qs[1][ln * 4] + v1 * sm.qs[1][ln * 4 + 1] +
                       v2 * sm.qs[1][ln * 4 + 2] + v3 * sm.qs[1][ln * 4 + 3];
            float d2 = v0 * sm.qs[2][ln * 4] + v1 * sm.qs[2][ln * 4 + 1] +
                       v2 * sm.qs[2][ln * 4 + 2] + v3 * sm.qs[2][ln * 4 + 3];
            for (int off = 32; off >= 1; off >>= 1) {
                d0 += __shfl_xor(d0, off, 64);
                d1 += __shfl_xor(d1, off, 64);
                d2 += __shfl_xor(d2, off, 64);
            }
            if (ln == 0) { sm.al[0][s] = d0; sm.al[1][s] = d1; sm.al[2][s] = d2; }
        }
        __syncthreads();
        if (wv < 3) {
            float v = sm.al[wv][ln];
            float mx = v;
            for (int off = 32; off >= 1; off >>= 1) mx = fmaxf(mx, __shfl_xor(mx, off, 64));
            float e = expf(v - mx);
            float s = e;
            for (int off = 32; off >= 1; off >>= 1) s += __shfl_xor(s, off, 64);
            sm.al[wv][ln] = e / s;
        }
        __syncthreads();
        float a0 = 0.f, a1 = 0.f, a2 = 0.f;
        for (int s = 0; s < 64; ++s) {
            float xv = bfl((unsigned)sm.xs[s * 256 + tid]);
            a0 += sm.al[0][s] * xv;
            a1 += sm.al[1][s] * xv;
            a2 += sm.al[2][s] * xv;
        }
        float part = sm.qs[0][tid] * Wg[tid] + a0 * Wg[256 + tid] +
                     sm.qs[1][tid] * Wg[512 + tid] + a1 * Wg[768 + tid] +
                     sm.qs[2][tid] * Wg[1024 + tid] + a2 * Wg[1280 + tid];
        for (int off = 32; off >= 1; off >>= 1) part += __shfl_xor(part, off, 64);
        if (ln == 0) sm.wsum[wv] = part;
        __syncthreads();
        if (tid == 0) xg[p] = sm.wsum[0] + sm.wsum[1] + sm.wsum[2] + sm.wsum[3] + bg[0];
    }
    gridbar(bar, gen);

    // ---- P9: head (block 0) ----
    if (bx == 0) {
        float* z = sm.u.fin.z;
        z[tid] = xg[tid];
        z[256 + tid] = xg[256 + tid];
        __syncthreads();
        float acc = bl1[tid];
        const float* w = Wl1 + (size_t)tid * 512;
        for (int k = 0; k < 512; ++k) acc += w[k] * z[k];
        sm.u.fin.z1[tid] = tanhf(acc);
        __syncthreads();
        if (tid < 64) {
            float a = bl2[tid];
            const float* w2 = Wl2 + (size_t)tid * 256;
            for (int k = 0; k < 256; ++k) a += w2[k] * sm.u.fin.z1[k];
            sm.u.fin.z2[tid] = fmaxf(a, 0.f);
        }
        __syncthreads();
        if (tid < 64) {
            float v = Wl3[tid] * sm.u.fin.z2[tid];
            for (int off = 32; off >= 1; off >>= 1) v += __shfl_xor(v, off, 64);
            if (tid == 0) out[0] = 1.f / (1.f + expf(-(v + bl3[0])));
        }
    }
}

// ---------------- launch ----------------
extern "C" void kernel_launch(void* const* d_in, const int* in_sizes, int n_in,
                              void* d_out, int out_size, void* d_ws, size_t ws_size,
                              hipStream_t stream) {
    const float* h0 = (const float*)d_in[0];
    const int* src = (const int*)d_in[1];
    const int* dst = (const int*)d_in[2];
    const int* path = (const int*)d_in[3];
    const float* W1 = (const float*)d_in[4];
    const float* b1 = (const float*)d_in[5];
    const float* W2 = (const float*)d_in[6];
    const float* b2 = (const float*)d_in[7];
    const float* W3 = (const float*)d_in[8];
    const float* b3 = (const float*)d_in[9];
    const float* W4 = (const float*)d_in[10];
    const float* b4 = (const float*)d_in[11];
    const float* Wih = (const float*)d_in[12];
    const float* Whh = (const float*)d_in[13];
    const float* bih = (const float*)d_in[14];
    const float* bhh = (const float*)d_in[15];
    const float* Wg = (const float*)d_in[16];
    const float* bg = (const float*)d_in[17];
    const float* Wl1 = (const float*)d_in[18];
    const float* bl1 = (const float*)d_in[19];
    const float* Wl2 = (const float*)d_in[20];
    const float* bl2 = (const float*)d_in[21];
    const float* Wl3 = (const float*)d_in[22];
    const float* bl3 = (const float*)d_in[23];

    char* ws = (char*)d_ws;
    int* counts = (int*)(ws + 0);                              // 2,560,000
    unsigned short* bins = (unsigned short*)(ws + 2621440);    // 3,840,000
    unsigned short* shA24 = (unsigned short*)(ws + 6553600);   // 960,000
    unsigned short* shB64 = (unsigned short*)(ws + 7602176);   // 2,560,000
    unsigned short* shA128 = (unsigned short*)(ws + 10485760); // 5,120,000
    unsigned short* h4b = (unsigned short*)(ws + 15728640);    // 10,240,000
    unsigned short* r0b = (unsigned short*)(ws + 26214400);    // 786,432
    float* gates_all = (float*)(ws + 27000832);                // 6,291,456
    float* cpart_all = (float*)(ws + 33292288);                // 12,288
    float* xg = (float*)(ws + 33357824);                       // 2,048
    unsigned short* Wb2p = (unsigned short*)(ws + 33423360);   // 4,096
    unsigned short* Wb3 = (unsigned short*)(ws + 33488896);    // 16,384
    unsigned short* Wb4 = (unsigned short*)(ws + 33554432);    // 65,536
    unsigned short* Wihb = (unsigned short*)(ws + 33619968);   // 1,572,864
    int* bar = (int*)(ws + 35192832);                          // 8

    init_all<<<3072, 256, 0, stream>>>(W2, W3, W4, Wih, counts, bar, Wb2p, Wb3, Wb4, Wihb);
    mega<<<GB, 256, 0, stream>>>(h0, src, dst, path, W1, b1, b2, b3, b4,
                                 Wih, Whh, bih, bhh, Wg, bg,
                                 Wl1, bl1, Wl2, bl2, Wl3, bl3,
                                 counts, bins, shA24, shB64, shA128, h4b,
                                 r0b, gates_all, cpart_all, xg,
                                 Wb2p, Wb3, Wb4, Wihb, bar, (float*)d_out);
}

// Round 4
// 331.026 us; speedup vs baseline: 6.1450x; 6.1450x over previous
//
#include <hip/hip_runtime.h>
#include <hip/hip_bf16.h>
#include <math.h>

#define N_NODES 20000
#define N_EDGES 640000
#define P_PATH 512
#define BIN_CAP 96     // max in-degree guard
#define CNT_STRIDE 32  // 1 counter per 128B line
#define NTILES 313     // ceil(20000/64)

typedef __attribute__((ext_vector_type(8))) short bf16x8;
typedef __attribute__((ext_vector_type(4))) float f32x4;

static __device__ __forceinline__ unsigned short f2bf(float f) {
    unsigned int b = __float_as_uint(f);
    unsigned int r = (b + 0x7fffu + ((b >> 16) & 1u)) >> 16;
    return (unsigned short)r;
}
static __device__ __forceinline__ float bfl(unsigned int u) { return __uint_as_float(u << 16); }
static __device__ __forceinline__ float bfh(unsigned int u) { return __uint_as_float(u & 0xffff0000u); }
static __device__ __forceinline__ void bf16_acc(float4& acc, uint2 u) {
    acc.x += bfl(u.x); acc.y += bfh(u.x);
    acc.z += bfl(u.y); acc.w += bfh(u.y);
}
static __device__ __forceinline__ float sigm(float x) { return 1.f / (1.f + expf(-x)); }

// ---------------- init: zero counts, convert weights ----------------
__global__ __launch_bounds__(256) void init_all(const float* __restrict__ W2,
                                                const float* __restrict__ W3f,
                                                const float* __restrict__ W4f,
                                                const float* __restrict__ Wihf,
                                                int* __restrict__ counts,
                                                unsigned short* __restrict__ Wb2p,
                                                unsigned short* __restrict__ Wb3,
                                                unsigned short* __restrict__ Wb4,
                                                unsigned short* __restrict__ Wihb) {
    int i = blockIdx.x * 256 + threadIdx.x;  // grid covers 786432
    if (i < N_NODES * CNT_STRIDE) counts[i] = 0;
    if (i < 2048) {
        int r = i >> 5, c = i & 31;
        Wb2p[i] = (c < 24) ? f2bf(W2[r * 24 + c]) : (unsigned short)0;
    }
    if (i < 8192) Wb3[i] = f2bf(W3f[i]);
    if (i < 32768) Wb4[i] = f2bf(W4f[i]);
    {
        int m = i >> 18;
        int rem = i & 262143;
        int j = rem >> 8, k = rem & 255;
        Wihb[i] = f2bf(Wihf[((size_t)m * 1024 + j) * 512 + 256 + k]);
    }
}

// ---------------- binned adjacency ----------------
__global__ __launch_bounds__(256) void fill_bins(const int* __restrict__ src,
                                                 const int* __restrict__ dst,
                                                 int* __restrict__ counts,
                                                 unsigned short* __restrict__ bins, int n) {
    int e = blockIdx.x * 256 + threadIdx.x;
    if (e < n) {
        int node = dst[e];
        int pos = atomicAdd(&counts[node * CNT_STRIDE], 1);
        if (pos < BIN_CAP) bins[(size_t)node * BIN_CAP + pos] = (unsigned short)src[e];
    }
}

// gather (self + neighbor sum) of a 64-node tile into LDS, bf16 out.
// TPN threads per node, UPT uint2 (4 bf16) per thread; TPN*UPT == DIM4IN.
template <int TPN, int UPT, int DIM4IN, int DIM4OUT>
static __device__ void gather_tile(const unsigned short* __restrict__ hb,
                                   const int* __restrict__ counts,
                                   const unsigned short* __restrict__ bins,
                                   int node0, unsigned short* X, int tid) {
    const uint2* hp = reinterpret_cast<const uint2*>(hb);
    uint2* Xp = reinterpret_cast<uint2*>(X);
    if (tid < 64 * TPN) {
        int nl = tid / TPN;
        int sub = tid - nl * TPN;
        int d4b = sub * UPT;
        int node = node0 + nl;
        float4 acc[UPT];
#pragma unroll
        for (int u = 0; u < UPT; ++u) acc[u] = {0.f, 0.f, 0.f, 0.f};
        if (node < N_NODES) {
            const uint2* selfp = hp + (size_t)node * DIM4IN + d4b;
#pragma unroll
            for (int u = 0; u < UPT; ++u) bf16_acc(acc[u], selfp[u]);
            int cnt = counts[node * CNT_STRIDE];
            if (cnt > BIN_CAP) cnt = BIN_CAP;
            const unsigned short* bp = bins + (size_t)node * BIN_CAP;
            int e = 0;
            for (; e + 2 <= cnt; e += 2) {
                const uint2* r0 = hp + (size_t)bp[e] * DIM4IN + d4b;
                const uint2* r1 = hp + (size_t)bp[e + 1] * DIM4IN + d4b;
                uint2 t0[UPT], t1[UPT];
#pragma unroll
                for (int u = 0; u < UPT; ++u) { t0[u] = r0[u]; t1[u] = r1[u]; }
#pragma unroll
                for (int u = 0; u < UPT; ++u) { bf16_acc(acc[u], t0[u]); bf16_acc(acc[u], t1[u]); }
            }
            if (e < cnt) {
                const uint2* r0 = hp + (size_t)bp[e] * DIM4IN + d4b;
#pragma unroll
                for (int u = 0; u < UPT; ++u) bf16_acc(acc[u], r0[u]);
            }
        }
#pragma unroll
        for (int u = 0; u < UPT; ++u) {
            uint2 o;
            o.x = (unsigned)f2bf(acc[u].x) | ((unsigned)f2bf(acc[u].y) << 16);
            o.y = (unsigned)f2bf(acc[u].z) | ((unsigned)f2bf(acc[u].w) << 16);
            Xp[nl * DIM4OUT + d4b + u] = o;
        }
    }
}

// MFMA from LDS X [64][K] bf16: out = relu(X @ Wb^T + bias), bf16 store.
template <int K, int N>
static __device__ void mfma_store_bf(const unsigned short* X,
                                     const unsigned short* __restrict__ Wb,
                                     const float* __restrict__ bias,
                                     unsigned short* __restrict__ out, int row0, int tid) {
    constexpr int NT = N / 16, KC = K / 32;
    int ln = tid & 63, wv = tid >> 6;
    int lr = ln & 15, lk = ln >> 4;
    f32x4 acc[NT];
#pragma unroll
    for (int t = 0; t < NT; ++t) acc[t] = (f32x4){0.f, 0.f, 0.f, 0.f};
#pragma unroll
    for (int kc = 0; kc < KC; ++kc) {
        bf16x8 a = *reinterpret_cast<const bf16x8*>(&X[(wv * 16 + lr) * K + kc * 32 + lk * 8]);
#pragma unroll
        for (int t = 0; t < NT; ++t) {
            bf16x8 b = *reinterpret_cast<const bf16x8*>(&Wb[(size_t)(t * 16 + lr) * K + kc * 32 + lk * 8]);
            acc[t] = __builtin_amdgcn_mfma_f32_16x16x32_bf16(a, b, acc[t], 0, 0, 0);
        }
    }
#pragma unroll
    for (int t = 0; t < NT; ++t) {
        float bj = bias[t * 16 + lr];
#pragma unroll
        for (int r = 0; r < 4; ++r) {
            int row = row0 + wv * 16 + lk * 4 + r;
            if (row < N_NODES)
                out[(size_t)row * N + t * 16 + lr] = f2bf(fmaxf(acc[t][r] + bj, 0.f));
        }
    }
}

// ---------------- L1: fp32 gather (IN=8) + 8->24 matvec, one kernel ----------------
__global__ __launch_bounds__(256) void gin_l1(const float* __restrict__ h0,
                                              const int* __restrict__ counts,
                                              const unsigned short* __restrict__ bins,
                                              const float* __restrict__ W1,
                                              const float* __restrict__ b1,
                                              unsigned short* __restrict__ shA24) {
    __shared__ float XL1[64 * 8];
    int tid = threadIdx.x;
    int node0 = blockIdx.x * 64;
    float4* Xf = reinterpret_cast<float4*>(XL1);
    const float4* hp = reinterpret_cast<const float4*>(h0);
    for (int it = tid; it < 128; it += 256) {
        int nl = it >> 1, d4 = it & 1;
        int node = node0 + nl;
        float4 a = {0.f, 0.f, 0.f, 0.f};
        if (node < N_NODES) {
            a = hp[(size_t)node * 2 + d4];  // self
            int cnt = counts[node * CNT_STRIDE];
            if (cnt > BIN_CAP) cnt = BIN_CAP;
            const unsigned short* bp = bins + (size_t)node * BIN_CAP;
            int e = 0;
            for (; e + 4 <= cnt; e += 4) {
                float4 v0 = hp[(size_t)bp[e] * 2 + d4];
                float4 v1 = hp[(size_t)bp[e + 1] * 2 + d4];
                float4 v2 = hp[(size_t)bp[e + 2] * 2 + d4];
                float4 v3 = hp[(size_t)bp[e + 3] * 2 + d4];
                a.x += v0.x + v1.x + v2.x + v3.x;
                a.y += v0.y + v1.y + v2.y + v3.y;
                a.z += v0.z + v1.z + v2.z + v3.z;
                a.w += v0.w + v1.w + v2.w + v3.w;
            }
            for (; e < cnt; ++e) {
                float4 v = hp[(size_t)bp[e] * 2 + d4];
                a.x += v.x; a.y += v.y; a.z += v.z; a.w += v.w;
            }
        }
        Xf[it] = a;
    }
    __syncthreads();
    int nl = tid >> 2, jg = tid & 3;
    int node = node0 + nl;
    if (node < N_NODES) {
        const float* Xa = XL1 + nl * 8;
#pragma unroll
        for (int jj = 0; jj < 6; ++jj) {
            int j = jg * 6 + jj;
            float acc = b1[j];
#pragma unroll
            for (int k = 0; k < 8; ++k) acc += W1[j * 8 + k] * Xa[k];
            shA24[(size_t)node * 24 + j] = f2bf(fmaxf(acc, 0.f));
        }
    }
}

// ---------------- fused GIN layer: gather into LDS + MFMA, one dispatch ----------------
template <int TPN, int UPT, int D4IN, int D4OUT, int K, int N>
__global__ __launch_bounds__(256) void gin_layer(const unsigned short* __restrict__ hb_in,
                                                 const int* __restrict__ counts,
                                                 const unsigned short* __restrict__ bins,
                                                 const unsigned short* __restrict__ Wb,
                                                 const float* __restrict__ bias,
                                                 unsigned short* __restrict__ out_bf) {
    __shared__ unsigned short X[64 * K];
    int tid = threadIdx.x;
    int node0 = blockIdx.x * 64;
    gather_tile<TPN, UPT, D4IN, D4OUT>(hb_in, counts, bins, node0, X, tid);
    if (D4OUT > D4IN) {
        constexpr int NPAD = 64 * (D4OUT - D4IN);
        if (tid >= 64 * TPN && tid < 64 * TPN + NPAD) {
            int it = tid - 64 * TPN;
            int nl = it / (D4OUT - D4IN);
            int dp = D4IN + it % (D4OUT - D4IN);
            uint2 z; z.x = 0u; z.y = 0u;
            reinterpret_cast<uint2*>(X)[nl * D4OUT + dp] = z;
        }
    }
    __syncthreads();
    mfma_store_bf<K, N>(X, Wb, bias, out_bf, node0, tid);
}

// ---------------- attn pass 1 (q=hs1) + r0b + cpart ----------------
__global__ __launch_bounds__(256) void attn1_cpart(const unsigned short* __restrict__ h4b,
                                                   const int* __restrict__ path,
                                                   const float* __restrict__ Wih,
                                                   const float* __restrict__ Whh,
                                                   const float* __restrict__ bih,
                                                   const float* __restrict__ bhh,
                                                   unsigned short* __restrict__ r0b,
                                                   float* __restrict__ cpart_all) {
    int p = blockIdx.x;
    __shared__ unsigned short xs[64 * 256];
    __shared__ float qs[3][256];
    __shared__ float al[3][64];
    __shared__ int nodes[64];
    int tid = threadIdx.x;
    int ln = tid & 63, wv = tid >> 6;
#pragma unroll
    for (int m = 0; m < 3; ++m) {
        const float* bi = bih + (size_t)m * 1024;
        const float* bh = bhh + (size_t)m * 1024;
        float gi = bi[tid] + bh[tid];
        float gg = bi[512 + tid] + bh[512 + tid];
        float go = bi[768 + tid] + bh[768 + tid];
        qs[m][tid] = sigm(go) * tanhf(sigm(gi) * tanhf(gg));  // hs1
    }
    if (tid < 64) nodes[tid] = path[p * 64 + tid];
    __syncthreads();
    const uint2* h4p = reinterpret_cast<const uint2*>(h4b);
    for (int s = wv; s < 64; s += 4) {
        uint2 u = h4p[(size_t)nodes[s] * 64 + ln];
        *reinterpret_cast<uint2*>(&xs[s * 256 + ln * 4]) = u;
        float v0 = bfl(u.x), v1 = bfh(u.x), v2 = bfl(u.y), v3 = bfh(u.y);
        float d0 = v0 * qs[0][ln * 4] + v1 * qs[0][ln * 4 + 1] +
                   v2 * qs[0][ln * 4 + 2] + v3 * qs[0][ln * 4 + 3];
        float d1 = v0 * qs[1][ln * 4] + v1 * qs[1][ln * 4 + 1] +
                   v2 * qs[1][ln * 4 + 2] + v3 * qs[1][ln * 4 + 3];
        float d2 = v0 * qs[2][ln * 4] + v1 * qs[2][ln * 4 + 1] +
                   v2 * qs[2][ln * 4 + 2] + v3 * qs[2][ln * 4 + 3];
        for (int off = 32; off >= 1; off >>= 1) {
            d0 += __shfl_xor(d0, off, 64);
            d1 += __shfl_xor(d1, off, 64);
            d2 += __shfl_xor(d2, off, 64);
        }
        if (ln == 0) { al[0][s] = d0; al[1][s] = d1; al[2][s] = d2; }
    }
    __syncthreads();
    if (wv < 3) {
        float v = al[wv][ln];
        float mx = v;
        for (int off = 32; off >= 1; off >>= 1) mx = fmaxf(mx, __shfl_xor(mx, off, 64));
        float e = expf(v - mx);
        float s = e;
        for (int off = 32; off >= 1; off >>= 1) s += __shfl_xor(s, off, 64);
        al[wv][ln] = e / s;
    }
    __syncthreads();
    float a0 = 0.f, a1 = 0.f, a2 = 0.f;
    for (int s = 0; s < 64; ++s) {
        float xv = bfl((unsigned)xs[s * 256 + tid]);
        a0 += al[0][s] * xv;
        a1 += al[1][s] * xv;
        a2 += al[2][s] * xv;
    }
    r0b[((size_t)0 * P_PATH + p) * 256 + tid] = f2bf(a0);
    r0b[((size_t)1 * P_PATH + p) * 256 + tid] = f2bf(a1);
    r0b[((size_t)2 * P_PATH + p) * 256 + tid] = f2bf(a2);
    // cpart: 6 outputs per block (3072 total), wave-dots of length 256
#pragma unroll
    for (int rep = 0; rep < 2; ++rep) {
        int qi = wv + rep * 4;
        if (qi < 6) {
            int o = p * 6 + qi;
            int m = o >> 10, j = o & 1023;
            float4 wiv = reinterpret_cast<const float4*>(Wih + ((size_t)m * 1024 + j) * 512)[ln];
            float4 whv = reinterpret_cast<const float4*>(Whh + ((size_t)m * 1024 + j) * 256)[ln];
            float4 hv = *reinterpret_cast<const float4*>(&qs[m][ln * 4]);
            float acc = hv.x * (wiv.x + whv.x) + hv.y * (wiv.y + whv.y) +
                        hv.z * (wiv.z + whv.z) + hv.w * (wiv.w + whv.w);
            for (int off = 32; off >= 1; off >>= 1) acc += __shfl_xor(acc, off, 64);
            if (ln == 0) cpart_all[o] = acc + bih[o] + bhh[o];
        }
    }
}

// ---------------- gates MFMA: gates = r0b @ Wihb^T + cpart ----------------
__global__ __launch_bounds__(256) void mfma_gates(const unsigned short* __restrict__ r0b,
                                                  const unsigned short* __restrict__ Wihb,
                                                  const float* __restrict__ cpart_all,
                                                  float* __restrict__ gates_all) {
    int m = blockIdx.z;
    int p0 = blockIdx.x * 64;
    int j0 = blockIdx.y * 256;
    const unsigned short* A = r0b + (size_t)m * 512 * 256;
    const unsigned short* B = Wihb + (size_t)m * 1024 * 256 + (size_t)j0 * 256;
    const float* bias = cpart_all + m * 1024 + j0;
    float* og = gates_all + (size_t)m * 512 * 1024;
    int tid = threadIdx.x;
    int ln = tid & 63, wv = tid >> 6;
    int lr = ln & 15, lk = ln >> 4;
    int row0 = p0 + wv * 16;
    f32x4 acc[16];
#pragma unroll
    for (int t = 0; t < 16; ++t) acc[t] = (f32x4){0.f, 0.f, 0.f, 0.f};
#pragma unroll
    for (int kc = 0; kc < 8; ++kc) {
        bf16x8 a = *reinterpret_cast<const bf16x8*>(&A[(size_t)(row0 + lr) * 256 + kc * 32 + lk * 8]);
#pragma unroll
        for (int t = 0; t < 16; ++t) {
            bf16x8 b = *reinterpret_cast<const bf16x8*>(&B[(size_t)(t * 16 + lr) * 256 + kc * 32 + lk * 8]);
            acc[t] = __builtin_amdgcn_mfma_f32_16x16x32_bf16(a, b, acc[t], 0, 0, 0);
        }
    }
#pragma unroll
    for (int t = 0; t < 16; ++t) {
        float bj = bias[t * 16 + lr];
#pragma unroll
        for (int rr = 0; rr < 4; ++rr) {
            int row = row0 + lk * 4 + rr;
            og[(size_t)row * 1024 + j0 + t * 16 + lr] = acc[t][rr] + bj;
        }
    }
}

// ---------------- attn pass 2: LSTM pointwise + attention + xg ----------------
__global__ __launch_bounds__(256) void attn2(const unsigned short* __restrict__ h4b,
                                             const int* __restrict__ path,
                                             const float* __restrict__ gates_all,
                                             const float* __restrict__ bih,
                                             const float* __restrict__ bhh,
                                             const float* __restrict__ Wg,
                                             const float* __restrict__ bg,
                                             float* __restrict__ xg) {
    int p = blockIdx.x;
    __shared__ unsigned short xs[64 * 256];
    __shared__ float qs[3][256];
    __shared__ float al[3][64];
    __shared__ float wsum[4];
    __shared__ int nodes[64];
    int tid = threadIdx.x;
    int ln = tid & 63, wv = tid >> 6;
#pragma unroll
    for (int m = 0; m < 3; ++m) {
        const float* bi = bih + (size_t)m * 1024;
        const float* bh = bhh + (size_t)m * 1024;
        float gi0 = bi[tid] + bh[tid];
        float gg0 = bi[512 + tid] + bh[512 + tid];
        float c0 = sigm(gi0) * tanhf(gg0);
        const float* g = gates_all + ((size_t)m * P_PATH + p) * 1024;
        float gi = g[tid], gf = g[256 + tid], gg = g[512 + tid], go = g[768 + tid];
        float c1 = sigm(gf) * c0 + sigm(gi) * tanhf(gg);
        qs[m][tid] = sigm(go) * tanhf(c1);  // hs2 = q2
    }
    if (tid < 64) nodes[tid] = path[p * 64 + tid];
    __syncthreads();
    const uint2* h4p = reinterpret_cast<const uint2*>(h4b);
    for (int s = wv; s < 64; s += 4) {
        uint2 u = h4p[(size_t)nodes[s] * 64 + ln];
        *reinterpret_cast<uint2*>(&xs[s * 256 + ln * 4]) = u;
        float v0 = bfl(u.x), v1 = bfh(u.x), v2 = bfl(u.y), v3 = bfh(u.y);
        float d0 = v0 * qs[0][ln * 4] + v1 * qs[0][ln * 4 + 1] +
                   v2 * qs[0][ln * 4 + 2] + v3 * qs[0][ln * 4 + 3];
        float d1 = v0 * qs[1][ln * 4] + v1 * qs[1][ln * 4 + 1] +
                   v2 * qs[1][ln * 4 + 2] + v3 * qs[1][ln * 4 + 3];
        float d2 = v0 * qs[2][ln * 4] + v1 * qs[2][ln * 4 + 1] +
                   v2 * qs[2][ln * 4 + 2] + v3 * qs[2][ln * 4 + 3];
        for (int off = 32; off >= 1; off >>= 1) {
            d0 += __shfl_xor(d0, off, 64);
            d1 += __shfl_xor(d1, off, 64);
            d2 += __shfl_xor(d2, off, 64);
        }
        if (ln == 0) { al[0][s] = d0; al[1][s] = d1; al[2][s] = d2; }
    }
    __syncthreads();
    if (wv < 3) {
        float v = al[wv][ln];
        float mx = v;
        for (int off = 32; off >= 1; off >>= 1) mx = fmaxf(mx, __shfl_xor(mx, off, 64));
        float e = expf(v - mx);
        float s = e;
        for (int off = 32; off >= 1; off >>= 1) s += __shfl_xor(s, off, 64);
        al[wv][ln] = e / s;
    }
    __syncthreads();
    float a0 = 0.f, a1 = 0.f, a2 = 0.f;
    for (int s = 0; s < 64; ++s) {
        float xv = bfl((unsigned)xs[s * 256 + tid]);
        a0 += al[0][s] * xv;
        a1 += al[1][s] * xv;
        a2 += al[2][s] * xv;
    }
    float part = qs[0][tid] * Wg[tid] + a0 * Wg[256 + tid] +
                 qs[1][tid] * Wg[512 + tid] + a1 * Wg[768 + tid] +
                 qs[2][tid] * Wg[1024 + tid] + a2 * Wg[1280 + tid];
    for (int off = 32; off >= 1; off >>= 1) part += __shfl_xor(part, off, 64);
    if (ln == 0) wsum[wv] = part;
    __syncthreads();
    if (tid == 0) xg[p] = wsum[0] + wsum[1] + wsum[2] + wsum[3] + bg[0];
}

// ---------------- head ----------------
__global__ __launch_bounds__(256) void final_mlp(const float* __restrict__ xg,
                                                 const float* __restrict__ Wl1,
                                                 const float* __restrict__ bl1,
                                                 const float* __restrict__ Wl2,
                                                 const float* __restrict__ bl2,
                                                 const float* __restrict__ Wl3,
                                                 const float* __restrict__ bl3,
                                                 float* __restrict__ out) {
    __shared__ float z[512];
    __shared__ float z1[256];
    __shared__ float z2[64];
    int t = threadIdx.x;
    z[t] = xg[t];
    z[256 + t] = xg[256 + t];
    __syncthreads();
    float acc = bl1[t];
    const float* w = Wl1 + (size_t)t * 512;
    for (int k = 0; k < 512; ++k) acc += w[k] * z[k];
    z1[t] = tanhf(acc);
    __syncthreads();
    if (t < 64) {
        float a = bl2[t];
        const float* w2 = Wl2 + (size_t)t * 256;
        for (int k = 0; k < 256; ++k) a += w2[k] * z1[k];
        z2[t] = fmaxf(a, 0.f);
    }
    __syncthreads();
    if (t < 64) {
        float v = Wl3[t] * z2[t];
        for (int off = 32; off >= 1; off >>= 1) v += __shfl_xor(v, off, 64);
        if (t == 0) out[0] = 1.f / (1.f + expf(-(v + bl3[0])));
    }
}

// ---------------- launch ----------------
extern "C" void kernel_launch(void* const* d_in, const int* in_sizes, int n_in,
                              void* d_out, int out_size, void* d_ws, size_t ws_size,
                              hipStream_t stream) {
    const float* h0 = (const float*)d_in[0];
    const int* src = (const int*)d_in[1];
    const int* dst = (const int*)d_in[2];
    const int* path = (const int*)d_in[3];
    const float* W1 = (const float*)d_in[4];
    const float* b1 = (const float*)d_in[5];
    const float* W2 = (const float*)d_in[6];
    const float* b2 = (const float*)d_in[7];
    const float* W3 = (const float*)d_in[8];
    const float* b3 = (const float*)d_in[9];
    const float* W4 = (const float*)d_in[10];
    const float* b4 = (const float*)d_in[11];
    const float* Wih = (const float*)d_in[12];
    const float* Whh = (const float*)d_in[13];
    const float* bih = (const float*)d_in[14];
    const float* bhh = (const float*)d_in[15];
    const float* Wg = (const float*)d_in[16];
    const float* bg = (const float*)d_in[17];
    const float* Wl1 = (const float*)d_in[18];
    const float* bl1 = (const float*)d_in[19];
    const float* Wl2 = (const float*)d_in[20];
    const float* bl2 = (const float*)d_in[21];
    const float* Wl3 = (const float*)d_in[22];
    const float* bl3 = (const float*)d_in[23];

    char* ws = (char*)d_ws;
    int* counts = (int*)(ws + 0);                              // 2,560,000
    unsigned short* bins = (unsigned short*)(ws + 2621440);    // 3,840,000
    unsigned short* shA24 = (unsigned short*)(ws + 6553600);   // 963,072
    unsigned short* shB64 = (unsigned short*)(ws + 7602176);   // 2,568,192
    unsigned short* shA128 = (unsigned short*)(ws + 10485760); // 5,136,384
    unsigned short* h4b = (unsigned short*)(ws + 15728640);    // 10,272,768
    unsigned short* r0b = (unsigned short*)(ws + 26214400);    // 786,432
    float* gates_all = (float*)(ws + 27000832);                // 6,291,456
    float* cpart_all = (float*)(ws + 33292288);                // 12,288
    float* xg = (float*)(ws + 33357824);                       // 2,048
    unsigned short* Wb2p = (unsigned short*)(ws + 33423360);   // 4,096
    unsigned short* Wb3 = (unsigned short*)(ws + 33488896);    // 16,384
    unsigned short* Wb4 = (unsigned short*)(ws + 33554432);    // 65,536
    unsigned short* Wihb = (unsigned short*)(ws + 33619968);   // 1,572,864

    init_all<<<3072, 256, 0, stream>>>(W2, W3, W4, Wih, counts, Wb2p, Wb3, Wb4, Wihb);
    fill_bins<<<(N_EDGES + 255) / 256, 256, 0, stream>>>(src, dst, counts, bins, N_EDGES);

    gin_l1<<<NTILES, 256, 0, stream>>>(h0, counts, bins, W1, b1, shA24);
    gin_layer<2, 3, 6, 8, 32, 64><<<NTILES, 256, 0, stream>>>(shA24, counts, bins, Wb2p, b2, shB64);
    gin_layer<4, 4, 16, 16, 64, 128><<<NTILES, 256, 0, stream>>>(shB64, counts, bins, Wb3, b3, shA128);
    gin_layer<4, 8, 32, 32, 128, 256><<<NTILES, 256, 0, stream>>>(shA128, counts, bins, Wb4, b4, h4b);

    attn1_cpart<<<P_PATH, 256, 0, stream>>>(h4b, path, Wih, Whh, bih, bhh, r0b, cpart_all);
    mfma_gates<<<dim3(8, 4, 3), 256, 0, stream>>>(r0b, Wihb, cpart_all, gates_all);
    attn2<<<P_PATH, 256, 0, stream>>>(h4b, path, gates_all, bih, bhh, Wg, bg, xg);
    final_mlp<<<1, 256, 0, stream>>>(xg, Wl1, bl1, Wl2, bl2, Wl3, bl3, (float*)d_out);
}

// Round 5
// 274.314 us; speedup vs baseline: 7.4154x; 1.2067x over previous
//
#include <hip/hip_runtime.h>
#include <hip/hip_bf16.h>
#include <math.h>

#define N_NODES 20000
#define N_EDGES 640000
#define P_PATH 512
#define BIN_CAP 96     // max in-degree guard
#define CNT_STRIDE 32  // 1 counter per 128B line
#define NTILES64 313   // ceil(20000/64) for L1

typedef __attribute__((ext_vector_type(8))) short bf16x8;
typedef __attribute__((ext_vector_type(4))) float f32x4;

static __device__ __forceinline__ unsigned short f2bf(float f) {
    unsigned int b = __float_as_uint(f);
    unsigned int r = (b + 0x7fffu + ((b >> 16) & 1u)) >> 16;
    return (unsigned short)r;
}
static __device__ __forceinline__ float bfl(unsigned int u) { return __uint_as_float(u << 16); }
static __device__ __forceinline__ float bfh(unsigned int u) { return __uint_as_float(u & 0xffff0000u); }
static __device__ __forceinline__ void bf16_acc(float4& acc, uint2 u) {
    acc.x += bfl(u.x); acc.y += bfh(u.x);
    acc.z += bfl(u.y); acc.w += bfh(u.y);
}
static __device__ __forceinline__ float sigm(float x) { return 1.f / (1.f + expf(-x)); }

// ---------------- init: zero counts, convert weights ----------------
__global__ __launch_bounds__(256) void init_all(const float* __restrict__ W2,
                                                const float* __restrict__ W3f,
                                                const float* __restrict__ W4f,
                                                const float* __restrict__ Wihf,
                                                int* __restrict__ counts,
                                                unsigned short* __restrict__ Wb2p,
                                                unsigned short* __restrict__ Wb3,
                                                unsigned short* __restrict__ Wb4,
                                                unsigned short* __restrict__ Wihb) {
    int i = blockIdx.x * 256 + threadIdx.x;  // grid covers 786432
    if (i < N_NODES * CNT_STRIDE) counts[i] = 0;
    if (i < 2048) {
        int r = i >> 5, c = i & 31;
        Wb2p[i] = (c < 24) ? f2bf(W2[r * 24 + c]) : (unsigned short)0;
    }
    if (i < 8192) Wb3[i] = f2bf(W3f[i]);
    if (i < 32768) Wb4[i] = f2bf(W4f[i]);
    {
        int m = i >> 18;
        int rem = i & 262143;
        int j = rem >> 8, k = rem & 255;
        Wihb[i] = f2bf(Wihf[((size_t)m * 1024 + j) * 512 + 256 + k]);
    }
}

// ---------------- binned adjacency ----------------
__global__ __launch_bounds__(256) void fill_bins(const int* __restrict__ src,
                                                 const int* __restrict__ dst,
                                                 int* __restrict__ counts,
                                                 unsigned short* __restrict__ bins, int n) {
    int e = blockIdx.x * 256 + threadIdx.x;
    if (e < n) {
        int node = dst[e];
        int pos = atomicAdd(&counts[node * CNT_STRIDE], 1);
        if (pos < BIN_CAP) bins[(size_t)node * BIN_CAP + pos] = (unsigned short)src[e];
    }
}

// ---------------- L1: fp32 gather (IN=8) + 8->24 matvec, 32-padded bf16 out ----------------
__global__ __launch_bounds__(256) void gin_l1(const float* __restrict__ h0,
                                              const int* __restrict__ counts,
                                              const unsigned short* __restrict__ bins,
                                              const float* __restrict__ W1,
                                              const float* __restrict__ b1,
                                              unsigned short* __restrict__ shA32) {
    __shared__ float XL1[64 * 8];
    int tid = threadIdx.x;
    int node0 = blockIdx.x * 64;
    float4* Xf = reinterpret_cast<float4*>(XL1);
    const float4* hp = reinterpret_cast<const float4*>(h0);
    for (int it = tid; it < 128; it += 256) {
        int nl = it >> 1, d4 = it & 1;
        int node = node0 + nl;
        float4 a = {0.f, 0.f, 0.f, 0.f};
        if (node < N_NODES) {
            a = hp[(size_t)node * 2 + d4];  // self
            int cnt = counts[node * CNT_STRIDE];
            if (cnt > BIN_CAP) cnt = BIN_CAP;
            const unsigned short* bp = bins + (size_t)node * BIN_CAP;
            int e = 0;
            for (; e + 4 <= cnt; e += 4) {
                float4 v0 = hp[(size_t)bp[e] * 2 + d4];
                float4 v1 = hp[(size_t)bp[e + 1] * 2 + d4];
                float4 v2 = hp[(size_t)bp[e + 2] * 2 + d4];
                float4 v3 = hp[(size_t)bp[e + 3] * 2 + d4];
                a.x += v0.x + v1.x + v2.x + v3.x;
                a.y += v0.y + v1.y + v2.y + v3.y;
                a.z += v0.z + v1.z + v2.z + v3.z;
                a.w += v0.w + v1.w + v2.w + v3.w;
            }
            for (; e < cnt; ++e) {
                float4 v = hp[(size_t)bp[e] * 2 + d4];
                a.x += v.x; a.y += v.y; a.z += v.z; a.w += v.w;
            }
        }
        Xf[it] = a;
    }
    __syncthreads();
    int nl = tid >> 2, jg = tid & 3;
    int node = node0 + nl;
    if (node < N_NODES) {
        const float* Xa = XL1 + nl * 8;
#pragma unroll
        for (int jj = 0; jj < 6; ++jj) {
            int j = jg * 6 + jj;
            float acc = b1[j];
#pragma unroll
            for (int k = 0; k < 8; ++k) acc += W1[j * 8 + k] * Xa[k];
            shA32[(size_t)node * 32 + j] = f2bf(fmaxf(acc, 0.f));
        }
        // zero pad cols 24..31 (each of the 4 jg threads zeros 2)
        shA32[(size_t)node * 32 + 24 + jg * 2] = 0;
        shA32[(size_t)node * 32 + 25 + jg * 2] = 0;
    }
}

// ---------------- fused GIN layer: small node tile (high grid), gather + MFMA ----------------
// NODES nodes/block, TPN threads/node (NODES*TPN == 256), UPT uint2 per thread;
// D4 = TPN*UPT = K/4. MFMA: R=NODES/16 row groups, C=4/R col groups.
template <int NODES, int TPN, int UPT, int K, int N>
__global__ __launch_bounds__(256) void gin_layer2(const unsigned short* __restrict__ hb_in,
                                                  const int* __restrict__ counts,
                                                  const unsigned short* __restrict__ bins,
                                                  const unsigned short* __restrict__ Wb,
                                                  const float* __restrict__ bias,
                                                  unsigned short* __restrict__ out_bf) {
    constexpr int D4 = TPN * UPT;
    static_assert(D4 * 4 == K, "K mismatch");
    __shared__ unsigned short X[NODES * K];
    int tid = threadIdx.x;
    int node0 = blockIdx.x * NODES;
    const uint2* hp = reinterpret_cast<const uint2*>(hb_in);
    uint2* Xp = reinterpret_cast<uint2*>(X);
    {
        int nl = tid / TPN;
        int sub = tid - nl * TPN;
        int d4b = sub * UPT;
        int node = node0 + nl;
        float4 acc[UPT];
#pragma unroll
        for (int u = 0; u < UPT; ++u) acc[u] = {0.f, 0.f, 0.f, 0.f};
        if (node < N_NODES) {
            const uint2* selfp = hp + (size_t)node * D4 + d4b;
#pragma unroll
            for (int u = 0; u < UPT; ++u) bf16_acc(acc[u], selfp[u]);
            int cnt = counts[node * CNT_STRIDE];
            if (cnt > BIN_CAP) cnt = BIN_CAP;
            const unsigned short* bp = bins + (size_t)node * BIN_CAP;
            int e = 0;
            for (; e + 4 <= cnt; e += 4) {
                const uint2* r0 = hp + (size_t)bp[e] * D4 + d4b;
                const uint2* r1 = hp + (size_t)bp[e + 1] * D4 + d4b;
                const uint2* r2 = hp + (size_t)bp[e + 2] * D4 + d4b;
                const uint2* r3 = hp + (size_t)bp[e + 3] * D4 + d4b;
                uint2 t0[UPT], t1[UPT], t2[UPT], t3[UPT];
#pragma unroll
                for (int u = 0; u < UPT; ++u) {
                    t0[u] = r0[u]; t1[u] = r1[u]; t2[u] = r2[u]; t3[u] = r3[u];
                }
#pragma unroll
                for (int u = 0; u < UPT; ++u) {
                    bf16_acc(acc[u], t0[u]); bf16_acc(acc[u], t1[u]);
                    bf16_acc(acc[u], t2[u]); bf16_acc(acc[u], t3[u]);
                }
            }
            for (; e < cnt; ++e) {
                const uint2* r0 = hp + (size_t)bp[e] * D4 + d4b;
#pragma unroll
                for (int u = 0; u < UPT; ++u) bf16_acc(acc[u], r0[u]);
            }
        }
#pragma unroll
        for (int u = 0; u < UPT; ++u) {
            uint2 o;
            o.x = (unsigned)f2bf(acc[u].x) | ((unsigned)f2bf(acc[u].y) << 16);
            o.y = (unsigned)f2bf(acc[u].z) | ((unsigned)f2bf(acc[u].w) << 16);
            Xp[nl * D4 + d4b + u] = o;
        }
    }
    __syncthreads();
    constexpr int R = NODES / 16;   // row groups
    constexpr int C = 4 / R;        // col groups (4 waves total)
    constexpr int NT = N / 16 / C;  // col tiles per wave
    constexpr int KC = K / 32;
    int ln = tid & 63, wv = tid >> 6;
    int rg = wv % R, cg = wv / R;
    int lr = ln & 15, lk = ln >> 4;
    int colbase = cg * (N / C);
    f32x4 acc[NT];
#pragma unroll
    for (int t = 0; t < NT; ++t) acc[t] = (f32x4){0.f, 0.f, 0.f, 0.f};
#pragma unroll
    for (int kc = 0; kc < KC; ++kc) {
        bf16x8 a = *reinterpret_cast<const bf16x8*>(&X[(rg * 16 + lr) * K + kc * 32 + lk * 8]);
#pragma unroll
        for (int t = 0; t < NT; ++t) {
            bf16x8 b = *reinterpret_cast<const bf16x8*>(
                &Wb[(size_t)(colbase + t * 16 + lr) * K + kc * 32 + lk * 8]);
            acc[t] = __builtin_amdgcn_mfma_f32_16x16x32_bf16(a, b, acc[t], 0, 0, 0);
        }
    }
#pragma unroll
    for (int t = 0; t < NT; ++t) {
        float bj = bias[colbase + t * 16 + lr];
#pragma unroll
        for (int r = 0; r < 4; ++r) {
            int row = node0 + rg * 16 + lk * 4 + r;
            if (row < N_NODES)
                out_bf[(size_t)row * N + colbase + t * 16 + lr] =
                    f2bf(fmaxf(acc[t][r] + bj, 0.f));
        }
    }
}

// ---------------- attn pass 1 (q=hs1) + r0b + cpart ----------------
__global__ __launch_bounds__(256) void attn1_cpart(const unsigned short* __restrict__ h4b,
                                                   const int* __restrict__ path,
                                                   const float* __restrict__ Wih,
                                                   const float* __restrict__ Whh,
                                                   const float* __restrict__ bih,
                                                   const float* __restrict__ bhh,
                                                   unsigned short* __restrict__ r0b,
                                                   float* __restrict__ cpart_all) {
    int p = blockIdx.x;
    __shared__ unsigned short xs[64 * 256];
    __shared__ float qs[3][256];
    __shared__ float al[3][64];
    __shared__ int nodes[64];
    int tid = threadIdx.x;
    int ln = tid & 63, wv = tid >> 6;
#pragma unroll
    for (int m = 0; m < 3; ++m) {
        const float* bi = bih + (size_t)m * 1024;
        const float* bh = bhh + (size_t)m * 1024;
        float gi = bi[tid] + bh[tid];
        float gg = bi[512 + tid] + bh[512 + tid];
        float go = bi[768 + tid] + bh[768 + tid];
        qs[m][tid] = sigm(go) * tanhf(sigm(gi) * tanhf(gg));  // hs1
    }
    if (tid < 64) nodes[tid] = path[p * 64 + tid];
    __syncthreads();
    const uint2* h4p = reinterpret_cast<const uint2*>(h4b);
    for (int s = wv; s < 64; s += 4) {
        uint2 u = h4p[(size_t)nodes[s] * 64 + ln];
        *reinterpret_cast<uint2*>(&xs[s * 256 + ln * 4]) = u;
        float v0 = bfl(u.x), v1 = bfh(u.x), v2 = bfl(u.y), v3 = bfh(u.y);
        float d0 = v0 * qs[0][ln * 4] + v1 * qs[0][ln * 4 + 1] +
                   v2 * qs[0][ln * 4 + 2] + v3 * qs[0][ln * 4 + 3];
        float d1 = v0 * qs[1][ln * 4] + v1 * qs[1][ln * 4 + 1] +
                   v2 * qs[1][ln * 4 + 2] + v3 * qs[1][ln * 4 + 3];
        float d2 = v0 * qs[2][ln * 4] + v1 * qs[2][ln * 4 + 1] +
                   v2 * qs[2][ln * 4 + 2] + v3 * qs[2][ln * 4 + 3];
        for (int off = 32; off >= 1; off >>= 1) {
            d0 += __shfl_xor(d0, off, 64);
            d1 += __shfl_xor(d1, off, 64);
            d2 += __shfl_xor(d2, off, 64);
        }
        if (ln == 0) { al[0][s] = d0; al[1][s] = d1; al[2][s] = d2; }
    }
    __syncthreads();
    if (wv < 3) {
        float v = al[wv][ln];
        float mx = v;
        for (int off = 32; off >= 1; off >>= 1) mx = fmaxf(mx, __shfl_xor(mx, off, 64));
        float e = expf(v - mx);
        float s = e;
        for (int off = 32; off >= 1; off >>= 1) s += __shfl_xor(s, off, 64);
        al[wv][ln] = e / s;
    }
    __syncthreads();
    float a0 = 0.f, a1 = 0.f, a2 = 0.f;
    for (int s = 0; s < 64; ++s) {
        float xv = bfl((unsigned)xs[s * 256 + tid]);
        a0 += al[0][s] * xv;
        a1 += al[1][s] * xv;
        a2 += al[2][s] * xv;
    }
    r0b[((size_t)0 * P_PATH + p) * 256 + tid] = f2bf(a0);
    r0b[((size_t)1 * P_PATH + p) * 256 + tid] = f2bf(a1);
    r0b[((size_t)2 * P_PATH + p) * 256 + tid] = f2bf(a2);
    // cpart: 6 outputs per block (3072 total), wave-dots of length 256
#pragma unroll
    for (int rep = 0; rep < 2; ++rep) {
        int qi = wv + rep * 4;
        if (qi < 6) {
            int o = p * 6 + qi;
            int m = o >> 10, j = o & 1023;
            float4 wiv = reinterpret_cast<const float4*>(Wih + ((size_t)m * 1024 + j) * 512)[ln];
            float4 whv = reinterpret_cast<const float4*>(Whh + ((size_t)m * 1024 + j) * 256)[ln];
            float4 hv = *reinterpret_cast<const float4*>(&qs[m][ln * 4]);
            float acc = hv.x * (wiv.x + whv.x) + hv.y * (wiv.y + whv.y) +
                        hv.z * (wiv.z + whv.z) + hv.w * (wiv.w + whv.w);
            for (int off = 32; off >= 1; off >>= 1) acc += __shfl_xor(acc, off, 64);
            if (ln == 0) cpart_all[o] = acc + bih[o] + bhh[o];
        }
    }
}

// ---------------- gates MFMA: 64x64 tiles, 384 blocks ----------------
__global__ __launch_bounds__(256) void mfma_gates(const unsigned short* __restrict__ r0b,
                                                  const unsigned short* __restrict__ Wihb,
                                                  const float* __restrict__ cpart_all,
                                                  float* __restrict__ gates_all) {
    int m = blockIdx.z;
    int p0 = blockIdx.x * 64;
    int j0 = blockIdx.y * 64;
    const unsigned short* A = r0b + (size_t)m * 512 * 256;
    const unsigned short* B = Wihb + (size_t)m * 1024 * 256 + (size_t)j0 * 256;
    const float* bias = cpart_all + m * 1024 + j0;
    float* og = gates_all + (size_t)m * 512 * 1024;
    int tid = threadIdx.x;
    int ln = tid & 63, wv = tid >> 6;
    int lr = ln & 15, lk = ln >> 4;
    int row0 = p0 + wv * 16;
    f32x4 acc[4];
#pragma unroll
    for (int t = 0; t < 4; ++t) acc[t] = (f32x4){0.f, 0.f, 0.f, 0.f};
#pragma unroll
    for (int kc = 0; kc < 8; ++kc) {
        bf16x8 a = *reinterpret_cast<const bf16x8*>(&A[(size_t)(row0 + lr) * 256 + kc * 32 + lk * 8]);
#pragma unroll
        for (int t = 0; t < 4; ++t) {
            bf16x8 b = *reinterpret_cast<const bf16x8*>(&B[(size_t)(t * 16 + lr) * 256 + kc * 32 + lk * 8]);
            acc[t] = __builtin_amdgcn_mfma_f32_16x16x32_bf16(a, b, acc[t], 0, 0, 0);
        }
    }
#pragma unroll
    for (int t = 0; t < 4; ++t) {
        float bj = bias[t * 16 + lr];
#pragma unroll
        for (int rr = 0; rr < 4; ++rr) {
            int row = row0 + lk * 4 + rr;
            og[(size_t)row * 1024 + j0 + t * 16 + lr] = acc[t][rr] + bj;
        }
    }
}

// ---------------- attn pass 2: LSTM pointwise + attention + xg ----------------
__global__ __launch_bounds__(256) void attn2(const unsigned short* __restrict__ h4b,
                                             const int* __restrict__ path,
                                             const float* __restrict__ gates_all,
                                             const float* __restrict__ bih,
                                             const float* __restrict__ bhh,
                                             const float* __restrict__ Wg,
                                             const float* __restrict__ bg,
                                             float* __restrict__ xg) {
    int p = blockIdx.x;
    __shared__ unsigned short xs[64 * 256];
    __shared__ float qs[3][256];
    __shared__ float al[3][64];
    __shared__ float wsum[4];
    __shared__ int nodes[64];
    int tid = threadIdx.x;
    int ln = tid & 63, wv = tid >> 6;
#pragma unroll
    for (int m = 0; m < 3; ++m) {
        const float* bi = bih + (size_t)m * 1024;
        const float* bh = bhh + (size_t)m * 1024;
        float gi0 = bi[tid] + bh[tid];
        float gg0 = bi[512 + tid] + bh[512 + tid];
        float c0 = sigm(gi0) * tanhf(gg0);
        const float* g = gates_all + ((size_t)m * P_PATH + p) * 1024;
        float gi = g[tid], gf = g[256 + tid], gg = g[512 + tid], go = g[768 + tid];
        float c1 = sigm(gf) * c0 + sigm(gi) * tanhf(gg);
        qs[m][tid] = sigm(go) * tanhf(c1);  // hs2 = q2
    }
    if (tid < 64) nodes[tid] = path[p * 64 + tid];
    __syncthreads();
    const uint2* h4p = reinterpret_cast<const uint2*>(h4b);
    for (int s = wv; s < 64; s += 4) {
        uint2 u = h4p[(size_t)nodes[s] * 64 + ln];
        *reinterpret_cast<uint2*>(&xs[s * 256 + ln * 4]) = u;
        float v0 = bfl(u.x), v1 = bfh(u.x), v2 = bfl(u.y), v3 = bfh(u.y);
        float d0 = v0 * qs[0][ln * 4] + v1 * qs[0][ln * 4 + 1] +
                   v2 * qs[0][ln * 4 + 2] + v3 * qs[0][ln * 4 + 3];
        float d1 = v0 * qs[1][ln * 4] + v1 * qs[1][ln * 4 + 1] +
                   v2 * qs[1][ln * 4 + 2] + v3 * qs[1][ln * 4 + 3];
        float d2 = v0 * qs[2][ln * 4] + v1 * qs[2][ln * 4 + 1] +
                   v2 * qs[2][ln * 4 + 2] + v3 * qs[2][ln * 4 + 3];
        for (int off = 32; off >= 1; off >>= 1) {
            d0 += __shfl_xor(d0, off, 64);
            d1 += __shfl_xor(d1, off, 64);
            d2 += __shfl_xor(d2, off, 64);
        }
        if (ln == 0) { al[0][s] = d0; al[1][s] = d1; al[2][s] = d2; }
    }
    __syncthreads();
    if (wv < 3) {
        float v = al[wv][ln];
        float mx = v;
        for (int off = 32; off >= 1; off >>= 1) mx = fmaxf(mx, __shfl_xor(mx, off, 64));
        float e = expf(v - mx);
        float s = e;
        for (int off = 32; off >= 1; off >>= 1) s += __shfl_xor(s, off, 64);
        al[wv][ln] = e / s;
    }
    __syncthreads();
    float a0 = 0.f, a1 = 0.f, a2 = 0.f;
    for (int s = 0; s < 64; ++s) {
        float xv = bfl((unsigned)xs[s * 256 + tid]);
        a0 += al[0][s] * xv;
        a1 += al[1][s] * xv;
        a2 += al[2][s] * xv;
    }
    float part = qs[0][tid] * Wg[tid] + a0 * Wg[256 + tid] +
                 qs[1][tid] * Wg[512 + tid] + a1 * Wg[768 + tid] +
                 qs[2][tid] * Wg[1024 + tid] + a2 * Wg[1280 + tid];
    for (int off = 32; off >= 1; off >>= 1) part += __shfl_xor(part, off, 64);
    if (ln == 0) wsum[wv] = part;
    __syncthreads();
    if (tid == 0) xg[p] = wsum[0] + wsum[1] + wsum[2] + wsum[3] + bg[0];
}

// ---------------- head ----------------
__global__ __launch_bounds__(256) void final_mlp(const float* __restrict__ xg,
                                                 const float* __restrict__ Wl1,
                                                 const float* __restrict__ bl1,
                                                 const float* __restrict__ Wl2,
                                                 const float* __restrict__ bl2,
                                                 const float* __restrict__ Wl3,
                                                 const float* __restrict__ bl3,
                                                 float* __restrict__ out) {
    __shared__ float z[512];
    __shared__ float z1[256];
    __shared__ float z2[64];
    int t = threadIdx.x;
    z[t] = xg[t];
    z[256 + t] = xg[256 + t];
    __syncthreads();
    float acc = bl1[t];
    const float* w = Wl1 + (size_t)t * 512;
    for (int k = 0; k < 512; ++k) acc += w[k] * z[k];
    z1[t] = tanhf(acc);
    __syncthreads();
    if (t < 64) {
        float a = bl2[t];
        const float* w2 = Wl2 + (size_t)t * 256;
        for (int k = 0; k < 256; ++k) a += w2[k] * z1[k];
        z2[t] = fmaxf(a, 0.f);
    }
    __syncthreads();
    if (t < 64) {
        float v = Wl3[t] * z2[t];
        for (int off = 32; off >= 1; off >>= 1) v += __shfl_xor(v, off, 64);
        if (t == 0) out[0] = 1.f / (1.f + expf(-(v + bl3[0])));
    }
}

// ---------------- launch ----------------
extern "C" void kernel_launch(void* const* d_in, const int* in_sizes, int n_in,
                              void* d_out, int out_size, void* d_ws, size_t ws_size,
                              hipStream_t stream) {
    const float* h0 = (const float*)d_in[0];
    const int* src = (const int*)d_in[1];
    const int* dst = (const int*)d_in[2];
    const int* path = (const int*)d_in[3];
    const float* W1 = (const float*)d_in[4];
    const float* b1 = (const float*)d_in[5];
    const float* W2 = (const float*)d_in[6];
    const float* b2 = (const float*)d_in[7];
    const float* W3 = (const float*)d_in[8];
    const float* b3 = (const float*)d_in[9];
    const float* W4 = (const float*)d_in[10];
    const float* b4 = (const float*)d_in[11];
    const float* Wih = (const float*)d_in[12];
    const float* Whh = (const float*)d_in[13];
    const float* bih = (const float*)d_in[14];
    const float* bhh = (const float*)d_in[15];
    const float* Wg = (const float*)d_in[16];
    const float* bg = (const float*)d_in[17];
    const float* Wl1 = (const float*)d_in[18];
    const float* bl1 = (const float*)d_in[19];
    const float* Wl2 = (const float*)d_in[20];
    const float* bl2 = (const float*)d_in[21];
    const float* Wl3 = (const float*)d_in[22];
    const float* bl3 = (const float*)d_in[23];

    char* ws = (char*)d_ws;
    int* counts = (int*)(ws + 0);                              // 2,560,000
    unsigned short* bins = (unsigned short*)(ws + 2621440);    // 3,840,000
    unsigned short* shA32 = (unsigned short*)(ws + 6553600);   // 1,280,000
    unsigned short* shB64 = (unsigned short*)(ws + 7864320);   // 2,560,000
    unsigned short* shA128 = (unsigned short*)(ws + 10485760); // 5,120,000
    unsigned short* h4b = (unsigned short*)(ws + 15728640);    // 10,240,000
    unsigned short* r0b = (unsigned short*)(ws + 26214400);    // 786,432
    float* gates_all = (float*)(ws + 27000832);                // 6,291,456
    float* cpart_all = (float*)(ws + 33292288);                // 12,288
    float* xg = (float*)(ws + 33357824);                       // 2,048
    unsigned short* Wb2p = (unsigned short*)(ws + 33423360);   // 4,096
    unsigned short* Wb3 = (unsigned short*)(ws + 33488896);    // 16,384
    unsigned short* Wb4 = (unsigned short*)(ws + 33554432);    // 65,536
    unsigned short* Wihb = (unsigned short*)(ws + 33619968);   // 1,572,864

    init_all<<<3072, 256, 0, stream>>>(W2, W3, W4, Wih, counts, Wb2p, Wb3, Wb4, Wihb);
    fill_bins<<<(N_EDGES + 255) / 256, 256, 0, stream>>>(src, dst, counts, bins, N_EDGES);

    gin_l1<<<NTILES64, 256, 0, stream>>>(h0, counts, bins, W1, b1, shA32);
    // L2: 32-node tiles (625 blocks), K=32 (24 padded), N=64
    gin_layer2<32, 8, 1, 32, 64><<<625, 256, 0, stream>>>(shA32, counts, bins, Wb2p, b2, shB64);
    // L3: 16-node tiles (1250 blocks), K=64, N=128
    gin_layer2<16, 16, 1, 64, 128><<<1250, 256, 0, stream>>>(shB64, counts, bins, Wb3, b3, shA128);
    // L4: 16-node tiles (1250 blocks), K=128, N=256
    gin_layer2<16, 16, 2, 128, 256><<<1250, 256, 0, stream>>>(shA128, counts, bins, Wb4, b4, h4b);

    attn1_cpart<<<P_PATH, 256, 0, stream>>>(h4b, path, Wih, Whh, bih, bhh, r0b, cpart_all);
    mfma_gates<<<dim3(8, 16, 3), 256, 0, stream>>>(r0b, Wihb, cpart_all, gates_all);
    attn2<<<P_PATH, 256, 0, stream>>>(h4b, path, gates_all, bih, bhh, Wg, bg, xg);
    final_mlp<<<1, 256, 0, stream>>>(xg, Wl1, bl1, Wl2, bl2, Wl3, bl3, (float*)d_out);
}

// Round 6
// 261.988 us; speedup vs baseline: 7.7643x; 1.0470x over previous
//
#include <hip/hip_runtime.h>
#include <hip/hip_bf16.h>
#include <math.h>

#define N_NODES 20000
#define N_EDGES 640000
#define P_PATH 512
#define BIN_CAP 96     // max in-degree guard
#define CNT_STRIDE 32  // 1 counter per 128B line
#define NTILES64 313   // ceil(20000/64) for L1

typedef __attribute__((ext_vector_type(8))) short bf16x8;
typedef __attribute__((ext_vector_type(4))) float f32x4;

static __device__ __forceinline__ unsigned short f2bf(float f) {
    unsigned int b = __float_as_uint(f);
    unsigned int r = (b + 0x7fffu + ((b >> 16) & 1u)) >> 16;
    return (unsigned short)r;
}
static __device__ __forceinline__ float bfl(unsigned int u) { return __uint_as_float(u << 16); }
static __device__ __forceinline__ float bfh(unsigned int u) { return __uint_as_float(u & 0xffff0000u); }
static __device__ __forceinline__ void bf16_acc(float4& acc, uint2 u) {
    acc.x += bfl(u.x); acc.y += bfh(u.x);
    acc.z += bfl(u.y); acc.w += bfh(u.y);
}
static __device__ __forceinline__ float sigm(float x) { return 1.f / (1.f + expf(-x)); }

// ---------------- init: zero counts, convert weights ----------------
__global__ __launch_bounds__(256) void init_all(const float* __restrict__ W2,
                                                const float* __restrict__ W3f,
                                                const float* __restrict__ W4f,
                                                const float* __restrict__ Wihf,
                                                const float* __restrict__ Wl1f,
                                                int* __restrict__ counts,
                                                unsigned short* __restrict__ Wb2p,
                                                unsigned short* __restrict__ Wb3,
                                                unsigned short* __restrict__ Wb4,
                                                unsigned short* __restrict__ Wihb,
                                                unsigned short* __restrict__ Wl1b) {
    int i = blockIdx.x * 256 + threadIdx.x;  // grid covers 786432
    if (i < N_NODES * CNT_STRIDE) counts[i] = 0;
    if (i < 2048) {
        int r = i >> 5, c = i & 31;
        Wb2p[i] = (c < 24) ? f2bf(W2[r * 24 + c]) : (unsigned short)0;
    }
    if (i < 8192) Wb3[i] = f2bf(W3f[i]);
    if (i < 32768) Wb4[i] = f2bf(W4f[i]);
    if (i < 131072) Wl1b[i] = f2bf(Wl1f[i]);
    {
        int m = i >> 18;
        int rem = i & 262143;
        int j = rem >> 8, k = rem & 255;
        Wihb[i] = f2bf(Wihf[((size_t)m * 1024 + j) * 512 + 256 + k]);
    }
}

// ---------------- binned adjacency ----------------
__global__ __launch_bounds__(256) void fill_bins(const int* __restrict__ src,
                                                 const int* __restrict__ dst,
                                                 int* __restrict__ counts,
                                                 unsigned short* __restrict__ bins, int n) {
    int e = blockIdx.x * 256 + threadIdx.x;
    if (e < n) {
        int node = dst[e];
        int pos = atomicAdd(&counts[node * CNT_STRIDE], 1);
        if (pos < BIN_CAP) bins[(size_t)node * BIN_CAP + pos] = (unsigned short)src[e];
    }
}

// ---------------- L1: fp32 gather (IN=8), 2-way neighbor split, + 8->24 matvec ----------------
__global__ __launch_bounds__(256) void gin_l1(const float* __restrict__ h0,
                                              const int* __restrict__ counts,
                                              const unsigned short* __restrict__ bins,
                                              const float* __restrict__ W1,
                                              const float* __restrict__ b1,
                                              unsigned short* __restrict__ shA32) {
    __shared__ float4 XP[64][2][2];  // [node][half][d4]
    int tid = threadIdx.x;
    int node0 = blockIdx.x * 64;
    const float4* hp = reinterpret_cast<const float4*>(h0);
    {
        int nl = tid >> 2;
        int d4 = (tid >> 1) & 1;
        int half = tid & 1;
        int node = node0 + nl;
        float4 a = {0.f, 0.f, 0.f, 0.f};
        if (node < N_NODES) {
            int cnt = counts[node * CNT_STRIDE];
            if (cnt > BIN_CAP) cnt = BIN_CAP;
            int lo = half ? (cnt >> 1) : 0;
            int hi = half ? cnt : (cnt >> 1);
            if (!half) {
                float4 s = hp[(size_t)node * 2 + d4];  // self term
                a.x += s.x; a.y += s.y; a.z += s.z; a.w += s.w;
            }
            const unsigned short* bp = bins + (size_t)node * BIN_CAP;
            int e = lo;
            for (; e + 4 <= hi; e += 4) {
                float4 v0 = hp[(size_t)bp[e] * 2 + d4];
                float4 v1 = hp[(size_t)bp[e + 1] * 2 + d4];
                float4 v2 = hp[(size_t)bp[e + 2] * 2 + d4];
                float4 v3 = hp[(size_t)bp[e + 3] * 2 + d4];
                a.x += v0.x + v1.x + v2.x + v3.x;
                a.y += v0.y + v1.y + v2.y + v3.y;
                a.z += v0.z + v1.z + v2.z + v3.z;
                a.w += v0.w + v1.w + v2.w + v3.w;
            }
            for (; e < hi; ++e) {
                float4 v = hp[(size_t)bp[e] * 2 + d4];
                a.x += v.x; a.y += v.y; a.z += v.z; a.w += v.w;
            }
        }
        XP[nl][half][d4] = a;
    }
    __syncthreads();
    int nl = tid >> 2, jg = tid & 3;
    int node = node0 + nl;
    if (node < N_NODES) {
        float4 x0a = XP[nl][0][0], x0b = XP[nl][1][0];
        float4 x1a = XP[nl][0][1], x1b = XP[nl][1][1];
        float x[8];
        x[0] = x0a.x + x0b.x; x[1] = x0a.y + x0b.y;
        x[2] = x0a.z + x0b.z; x[3] = x0a.w + x0b.w;
        x[4] = x1a.x + x1b.x; x[5] = x1a.y + x1b.y;
        x[6] = x1a.z + x1b.z; x[7] = x1a.w + x1b.w;
#pragma unroll
        for (int jj = 0; jj < 6; ++jj) {
            int j = jg * 6 + jj;
            float acc = b1[j];
#pragma unroll
            for (int k = 0; k < 8; ++k) acc += W1[j * 8 + k] * x[k];
            shA32[(size_t)node * 32 + j] = f2bf(fmaxf(acc, 0.f));
        }
        // zero pad cols 24..31 (each of the 4 jg threads zeros 2)
        shA32[(size_t)node * 32 + 24 + jg * 2] = 0;
        shA32[(size_t)node * 32 + 25 + jg * 2] = 0;
    }
}

// ---------------- fused GIN layer: small node tile, 8-deep gather ILP + MFMA ----------------
// NODES nodes/block, TPN threads/node (NODES*TPN == 256), UPT uint2 per thread;
// D4 = TPN*UPT = K/4. MFMA: R=NODES/16 row groups, C=4/R col groups.
template <int NODES, int TPN, int UPT, int K, int N>
__global__ __launch_bounds__(256) void gin_layer2(const unsigned short* __restrict__ hb_in,
                                                  const int* __restrict__ counts,
                                                  const unsigned short* __restrict__ bins,
                                                  const unsigned short* __restrict__ Wb,
                                                  const float* __restrict__ bias,
                                                  unsigned short* __restrict__ out_bf) {
    constexpr int D4 = TPN * UPT;
    static_assert(D4 * 4 == K, "K mismatch");
    __shared__ unsigned short X[NODES * K];
    int tid = threadIdx.x;
    int node0 = blockIdx.x * NODES;
    const uint2* hp = reinterpret_cast<const uint2*>(hb_in);
    uint2* Xp = reinterpret_cast<uint2*>(X);
    {
        int nl = tid / TPN;
        int sub = tid - nl * TPN;
        int d4b = sub * UPT;
        int node = node0 + nl;
        float4 acc[UPT];
#pragma unroll
        for (int u = 0; u < UPT; ++u) acc[u] = {0.f, 0.f, 0.f, 0.f};
        if (node < N_NODES) {
            const uint2* selfp = hp + (size_t)node * D4 + d4b;
#pragma unroll
            for (int u = 0; u < UPT; ++u) bf16_acc(acc[u], selfp[u]);
            int cnt = counts[node * CNT_STRIDE];
            if (cnt > BIN_CAP) cnt = BIN_CAP;
            const unsigned short* bp = bins + (size_t)node * BIN_CAP;
            int e = 0;
            for (; e + 8 <= cnt; e += 8) {
                uint4 bv = *reinterpret_cast<const uint4*>(bp + e);  // 8 ids, 16B aligned
                int s0 = bv.x & 0xffff, s1 = bv.x >> 16;
                int s2 = bv.y & 0xffff, s3 = bv.y >> 16;
                int s4 = bv.z & 0xffff, s5 = bv.z >> 16;
                int s6 = bv.w & 0xffff, s7 = bv.w >> 16;
                const uint2* r0 = hp + (size_t)s0 * D4 + d4b;
                const uint2* r1 = hp + (size_t)s1 * D4 + d4b;
                const uint2* r2 = hp + (size_t)s2 * D4 + d4b;
                const uint2* r3 = hp + (size_t)s3 * D4 + d4b;
                const uint2* r4 = hp + (size_t)s4 * D4 + d4b;
                const uint2* r5 = hp + (size_t)s5 * D4 + d4b;
                const uint2* r6 = hp + (size_t)s6 * D4 + d4b;
                const uint2* r7 = hp + (size_t)s7 * D4 + d4b;
                uint2 t0[UPT], t1[UPT], t2[UPT], t3[UPT];
                uint2 t4[UPT], t5[UPT], t6[UPT], t7[UPT];
#pragma unroll
                for (int u = 0; u < UPT; ++u) {
                    t0[u] = r0[u]; t1[u] = r1[u]; t2[u] = r2[u]; t3[u] = r3[u];
                    t4[u] = r4[u]; t5[u] = r5[u]; t6[u] = r6[u]; t7[u] = r7[u];
                }
#pragma unroll
                for (int u = 0; u < UPT; ++u) {
                    bf16_acc(acc[u], t0[u]); bf16_acc(acc[u], t1[u]);
                    bf16_acc(acc[u], t2[u]); bf16_acc(acc[u], t3[u]);
                    bf16_acc(acc[u], t4[u]); bf16_acc(acc[u], t5[u]);
                    bf16_acc(acc[u], t6[u]); bf16_acc(acc[u], t7[u]);
                }
            }
            for (; e < cnt; ++e) {
                const uint2* r0 = hp + (size_t)bp[e] * D4 + d4b;
#pragma unroll
                for (int u = 0; u < UPT; ++u) bf16_acc(acc[u], r0[u]);
            }
        }
#pragma unroll
        for (int u = 0; u < UPT; ++u) {
            uint2 o;
            o.x = (unsigned)f2bf(acc[u].x) | ((unsigned)f2bf(acc[u].y) << 16);
            o.y = (unsigned)f2bf(acc[u].z) | ((unsigned)f2bf(acc[u].w) << 16);
            Xp[nl * D4 + d4b + u] = o;
        }
    }
    __syncthreads();
    constexpr int R = NODES / 16;   // row groups
    constexpr int C = 4 / R;        // col groups (4 waves total)
    constexpr int NT = N / 16 / C;  // col tiles per wave
    constexpr int KC = K / 32;
    int ln = tid & 63, wv = tid >> 6;
    int rg = wv % R, cg = wv / R;
    int lr = ln & 15, lk = ln >> 4;
    int colbase = cg * (N / C);
    f32x4 acc[NT];
#pragma unroll
    for (int t = 0; t < NT; ++t) acc[t] = (f32x4){0.f, 0.f, 0.f, 0.f};
#pragma unroll
    for (int kc = 0; kc < KC; ++kc) {
        bf16x8 a = *reinterpret_cast<const bf16x8*>(&X[(rg * 16 + lr) * K + kc * 32 + lk * 8]);
#pragma unroll
        for (int t = 0; t < NT; ++t) {
            bf16x8 b = *reinterpret_cast<const bf16x8*>(
                &Wb[(size_t)(colbase + t * 16 + lr) * K + kc * 32 + lk * 8]);
            acc[t] = __builtin_amdgcn_mfma_f32_16x16x32_bf16(a, b, acc[t], 0, 0, 0);
        }
    }
#pragma unroll
    for (int t = 0; t < NT; ++t) {
        float bj = bias[colbase + t * 16 + lr];
#pragma unroll
        for (int r = 0; r < 4; ++r) {
            int row = node0 + rg * 16 + lk * 4 + r;
            if (row < N_NODES)
                out_bf[(size_t)row * N + colbase + t * 16 + lr] =
                    f2bf(fmaxf(acc[t][r] + bj, 0.f));
        }
    }
}

// ---------------- attn pass 1 (q=hs1) + r0b + cpart ----------------
__global__ __launch_bounds__(256) void attn1_cpart(const unsigned short* __restrict__ h4b,
                                                   const int* __restrict__ path,
                                                   const float* __restrict__ Wih,
                                                   const float* __restrict__ Whh,
                                                   const float* __restrict__ bih,
                                                   const float* __restrict__ bhh,
                                                   unsigned short* __restrict__ r0b,
                                                   float* __restrict__ cpart_all) {
    int p = blockIdx.x;
    __shared__ unsigned short xs[64 * 256];
    __shared__ float qs[3][256];
    __shared__ float al[3][64];
    __shared__ int nodes[64];
    int tid = threadIdx.x;
    int ln = tid & 63, wv = tid >> 6;
#pragma unroll
    for (int m = 0; m < 3; ++m) {
        const float* bi = bih + (size_t)m * 1024;
        const float* bh = bhh + (size_t)m * 1024;
        float gi = bi[tid] + bh[tid];
        float gg = bi[512 + tid] + bh[512 + tid];
        float go = bi[768 + tid] + bh[768 + tid];
        qs[m][tid] = sigm(go) * tanhf(sigm(gi) * tanhf(gg));  // hs1
    }
    if (tid < 64) nodes[tid] = path[p * 64 + tid];
    __syncthreads();
    const uint2* h4p = reinterpret_cast<const uint2*>(h4b);
    for (int s = wv; s < 64; s += 4) {
        uint2 u = h4p[(size_t)nodes[s] * 64 + ln];
        *reinterpret_cast<uint2*>(&xs[s * 256 + ln * 4]) = u;
        float v0 = bfl(u.x), v1 = bfh(u.x), v2 = bfl(u.y), v3 = bfh(u.y);
        float d0 = v0 * qs[0][ln * 4] + v1 * qs[0][ln * 4 + 1] +
                   v2 * qs[0][ln * 4 + 2] + v3 * qs[0][ln * 4 + 3];
        float d1 = v0 * qs[1][ln * 4] + v1 * qs[1][ln * 4 + 1] +
                   v2 * qs[1][ln * 4 + 2] + v3 * qs[1][ln * 4 + 3];
        float d2 = v0 * qs[2][ln * 4] + v1 * qs[2][ln * 4 + 1] +
                   v2 * qs[2][ln * 4 + 2] + v3 * qs[2][ln * 4 + 3];
        for (int off = 32; off >= 1; off >>= 1) {
            d0 += __shfl_xor(d0, off, 64);
            d1 += __shfl_xor(d1, off, 64);
            d2 += __shfl_xor(d2, off, 64);
        }
        if (ln == 0) { al[0][s] = d0; al[1][s] = d1; al[2][s] = d2; }
    }
    __syncthreads();
    if (wv < 3) {
        float v = al[wv][ln];
        float mx = v;
        for (int off = 32; off >= 1; off >>= 1) mx = fmaxf(mx, __shfl_xor(mx, off, 64));
        float e = expf(v - mx);
        float s = e;
        for (int off = 32; off >= 1; off >>= 1) s += __shfl_xor(s, off, 64);
        al[wv][ln] = e / s;
    }
    __syncthreads();
    float a0 = 0.f, a1 = 0.f, a2 = 0.f;
    for (int s = 0; s < 64; ++s) {
        float xv = bfl((unsigned)xs[s * 256 + tid]);
        a0 += al[0][s] * xv;
        a1 += al[1][s] * xv;
        a2 += al[2][s] * xv;
    }
    r0b[((size_t)0 * P_PATH + p) * 256 + tid] = f2bf(a0);
    r0b[((size_t)1 * P_PATH + p) * 256 + tid] = f2bf(a1);
    r0b[((size_t)2 * P_PATH + p) * 256 + tid] = f2bf(a2);
    // cpart: 6 outputs per block (3072 total), wave-dots of length 256
#pragma unroll
    for (int rep = 0; rep < 2; ++rep) {
        int qi = wv + rep * 4;
        if (qi < 6) {
            int o = p * 6 + qi;
            int m = o >> 10, j = o & 1023;
            float4 wiv = reinterpret_cast<const float4*>(Wih + ((size_t)m * 1024 + j) * 512)[ln];
            float4 whv = reinterpret_cast<const float4*>(Whh + ((size_t)m * 1024 + j) * 256)[ln];
            float4 hv = *reinterpret_cast<const float4*>(&qs[m][ln * 4]);
            float acc = hv.x * (wiv.x + whv.x) + hv.y * (wiv.y + whv.y) +
                        hv.z * (wiv.z + whv.z) + hv.w * (wiv.w + whv.w);
            for (int off = 32; off >= 1; off >>= 1) acc += __shfl_xor(acc, off, 64);
            if (ln == 0) cpart_all[o] = acc + bih[o] + bhh[o];
        }
    }
}

// ---------------- gates MFMA: 64x64 tiles, 384 blocks ----------------
__global__ __launch_bounds__(256) void mfma_gates(const unsigned short* __restrict__ r0b,
                                                  const unsigned short* __restrict__ Wihb,
                                                  const float* __restrict__ cpart_all,
                                                  float* __restrict__ gates_all) {
    int m = blockIdx.z;
    int p0 = blockIdx.x * 64;
    int j0 = blockIdx.y * 64;
    const unsigned short* A = r0b + (size_t)m * 512 * 256;
    const unsigned short* B = Wihb + (size_t)m * 1024 * 256 + (size_t)j0 * 256;
    const float* bias = cpart_all + m * 1024 + j0;
    float* og = gates_all + (size_t)m * 512 * 1024;
    int tid = threadIdx.x;
    int ln = tid & 63, wv = tid >> 6;
    int lr = ln & 15, lk = ln >> 4;
    int row0 = p0 + wv * 16;
    f32x4 acc[4];
#pragma unroll
    for (int t = 0; t < 4; ++t) acc[t] = (f32x4){0.f, 0.f, 0.f, 0.f};
#pragma unroll
    for (int kc = 0; kc < 8; ++kc) {
        bf16x8 a = *reinterpret_cast<const bf16x8*>(&A[(size_t)(row0 + lr) * 256 + kc * 32 + lk * 8]);
#pragma unroll
        for (int t = 0; t < 4; ++t) {
            bf16x8 b = *reinterpret_cast<const bf16x8*>(&B[(size_t)(t * 16 + lr) * 256 + kc * 32 + lk * 8]);
            acc[t] = __builtin_amdgcn_mfma_f32_16x16x32_bf16(a, b, acc[t], 0, 0, 0);
        }
    }
#pragma unroll
    for (int t = 0; t < 4; ++t) {
        float bj = bias[t * 16 + lr];
#pragma unroll
        for (int rr = 0; rr < 4; ++rr) {
            int row = row0 + lk * 4 + rr;
            og[(size_t)row * 1024 + j0 + t * 16 + lr] = acc[t][rr] + bj;
        }
    }
}

// ---------------- attn pass 2: LSTM pointwise + attention + xg ----------------
__global__ __launch_bounds__(256) void attn2(const unsigned short* __restrict__ h4b,
                                             const int* __restrict__ path,
                                             const float* __restrict__ gates_all,
                                             const float* __restrict__ bih,
                                             const float* __restrict__ bhh,
                                             const float* __restrict__ Wg,
                                             const float* __restrict__ bg,
                                             float* __restrict__ xg) {
    int p = blockIdx.x;
    __shared__ unsigned short xs[64 * 256];
    __shared__ float qs[3][256];
    __shared__ float al[3][64];
    __shared__ float wsum[4];
    __shared__ int nodes[64];
    int tid = threadIdx.x;
    int ln = tid & 63, wv = tid >> 6;
#pragma unroll
    for (int m = 0; m < 3; ++m) {
        const float* bi = bih + (size_t)m * 1024;
        const float* bh = bhh + (size_t)m * 1024;
        float gi0 = bi[tid] + bh[tid];
        float gg0 = bi[512 + tid] + bh[512 + tid];
        float c0 = sigm(gi0) * tanhf(gg0);
        const float* g = gates_all + ((size_t)m * P_PATH + p) * 1024;
        float gi = g[tid], gf = g[256 + tid], gg = g[512 + tid], go = g[768 + tid];
        float c1 = sigm(gf) * c0 + sigm(gi) * tanhf(gg);
        qs[m][tid] = sigm(go) * tanhf(c1);  // hs2 = q2
    }
    if (tid < 64) nodes[tid] = path[p * 64 + tid];
    __syncthreads();
    const uint2* h4p = reinterpret_cast<const uint2*>(h4b);
    for (int s = wv; s < 64; s += 4) {
        uint2 u = h4p[(size_t)nodes[s] * 64 + ln];
        *reinterpret_cast<uint2*>(&xs[s * 256 + ln * 4]) = u;
        float v0 = bfl(u.x), v1 = bfh(u.x), v2 = bfl(u.y), v3 = bfh(u.y);
        float d0 = v0 * qs[0][ln * 4] + v1 * qs[0][ln * 4 + 1] +
                   v2 * qs[0][ln * 4 + 2] + v3 * qs[0][ln * 4 + 3];
        float d1 = v0 * qs[1][ln * 4] + v1 * qs[1][ln * 4 + 1] +
                   v2 * qs[1][ln * 4 + 2] + v3 * qs[1][ln * 4 + 3];
        float d2 = v0 * qs[2][ln * 4] + v1 * qs[2][ln * 4 + 1] +
                   v2 * qs[2][ln * 4 + 2] + v3 * qs[2][ln * 4 + 3];
        for (int off = 32; off >= 1; off >>= 1) {
            d0 += __shfl_xor(d0, off, 64);
            d1 += __shfl_xor(d1, off, 64);
            d2 += __shfl_xor(d2, off, 64);
        }
        if (ln == 0) { al[0][s] = d0; al[1][s] = d1; al[2][s] = d2; }
    }
    __syncthreads();
    if (wv < 3) {
        float v = al[wv][ln];
        float mx = v;
        for (int off = 32; off >= 1; off >>= 1) mx = fmaxf(mx, __shfl_xor(mx, off, 64));
        float e = expf(v - mx);
        float s = e;
        for (int off = 32; off >= 1; off >>= 1) s += __shfl_xor(s, off, 64);
        al[wv][ln] = e / s;
    }
    __syncthreads();
    float a0 = 0.f, a1 = 0.f, a2 = 0.f;
    for (int s = 0; s < 64; ++s) {
        float xv = bfl((unsigned)xs[s * 256 + tid]);
        a0 += al[0][s] * xv;
        a1 += al[1][s] * xv;
        a2 += al[2][s] * xv;
    }
    float part = qs[0][tid] * Wg[tid] + a0 * Wg[256 + tid] +
                 qs[1][tid] * Wg[512 + tid] + a1 * Wg[768 + tid] +
                 qs[2][tid] * Wg[1024 + tid] + a2 * Wg[1280 + tid];
    for (int off = 32; off >= 1; off >>= 1) part += __shfl_xor(part, off, 64);
    if (ln == 0) wsum[wv] = part;
    __syncthreads();
    if (tid == 0) xg[p] = wsum[0] + wsum[1] + wsum[2] + wsum[3] + bg[0];
}

// ---------------- head (Wl1 in bf16) ----------------
__global__ __launch_bounds__(256) void final_mlp(const float* __restrict__ xg,
                                                 const unsigned short* __restrict__ Wl1b,
                                                 const float* __restrict__ bl1,
                                                 const float* __restrict__ Wl2,
                                                 const float* __restrict__ bl2,
                                                 const float* __restrict__ Wl3,
                                                 const float* __restrict__ bl3,
                                                 float* __restrict__ out) {
    __shared__ float z[512];
    __shared__ float z1[256];
    __shared__ float z2[64];
    int t = threadIdx.x;
    z[t] = xg[t];
    z[256 + t] = xg[256 + t];
    __syncthreads();
    float acc = bl1[t];
    const uint2* w = reinterpret_cast<const uint2*>(Wl1b + (size_t)t * 512);
    for (int k = 0; k < 128; ++k) {
        uint2 u = w[k];
        acc += bfl(u.x) * z[k * 4] + bfh(u.x) * z[k * 4 + 1] +
               bfl(u.y) * z[k * 4 + 2] + bfh(u.y) * z[k * 4 + 3];
    }
    z1[t] = tanhf(acc);
    __syncthreads();
    if (t < 64) {
        float a = bl2[t];
        const float* w2 = Wl2 + (size_t)t * 256;
        for (int k = 0; k < 256; ++k) a += w2[k] * z1[k];
        z2[t] = fmaxf(a, 0.f);
    }
    __syncthreads();
    if (t < 64) {
        float v = Wl3[t] * z2[t];
        for (int off = 32; off >= 1; off >>= 1) v += __shfl_xor(v, off, 64);
        if (t == 0) out[0] = 1.f / (1.f + expf(-(v + bl3[0])));
    }
}

// ---------------- launch ----------------
extern "C" void kernel_launch(void* const* d_in, const int* in_sizes, int n_in,
                              void* d_out, int out_size, void* d_ws, size_t ws_size,
                              hipStream_t stream) {
    const float* h0 = (const float*)d_in[0];
    const int* src = (const int*)d_in[1];
    const int* dst = (const int*)d_in[2];
    const int* path = (const int*)d_in[3];
    const float* W1 = (const float*)d_in[4];
    const float* b1 = (const float*)d_in[5];
    const float* W2 = (const float*)d_in[6];
    const float* b2 = (const float*)d_in[7];
    const float* W3 = (const float*)d_in[8];
    const float* b3 = (const float*)d_in[9];
    const float* W4 = (const float*)d_in[10];
    const float* b4 = (const float*)d_in[11];
    const float* Wih = (const float*)d_in[12];
    const float* Whh = (const float*)d_in[13];
    const float* bih = (const float*)d_in[14];
    const float* bhh = (const float*)d_in[15];
    const float* Wg = (const float*)d_in[16];
    const float* bg = (const float*)d_in[17];
    const float* Wl1 = (const float*)d_in[18];
    const float* bl1 = (const float*)d_in[19];
    const float* Wl2 = (const float*)d_in[20];
    const float* bl2 = (const float*)d_in[21];
    const float* Wl3 = (const float*)d_in[22];
    const float* bl3 = (const float*)d_in[23];

    char* ws = (char*)d_ws;
    int* counts = (int*)(ws + 0);                              // 2,560,000
    unsigned short* bins = (unsigned short*)(ws + 2621440);    // 3,840,000
    unsigned short* shA32 = (unsigned short*)(ws + 6553600);   // 1,280,000
    unsigned short* shB64 = (unsigned short*)(ws + 7864320);   // 2,560,000
    unsigned short* shA128 = (unsigned short*)(ws + 10485760); // 5,120,000
    unsigned short* h4b = (unsigned short*)(ws + 15728640);    // 10,240,000
    unsigned short* r0b = (unsigned short*)(ws + 26214400);    // 786,432
    float* gates_all = (float*)(ws + 27000832);                // 6,291,456
    float* cpart_all = (float*)(ws + 33292288);                // 12,288
    float* xg = (float*)(ws + 33357824);                       // 2,048
    unsigned short* Wb2p = (unsigned short*)(ws + 33423360);   // 4,096
    unsigned short* Wb3 = (unsigned short*)(ws + 33488896);    // 16,384
    unsigned short* Wb4 = (unsigned short*)(ws + 33554432);    // 65,536
    unsigned short* Wihb = (unsigned short*)(ws + 33619968);   // 1,572,864
    unsigned short* Wl1b = (unsigned short*)(ws + 35192832);   // 262,144

    init_all<<<3072, 256, 0, stream>>>(W2, W3, W4, Wih, Wl1, counts, Wb2p, Wb3, Wb4, Wihb, Wl1b);
    fill_bins<<<(N_EDGES + 255) / 256, 256, 0, stream>>>(src, dst, counts, bins, N_EDGES);

    gin_l1<<<NTILES64, 256, 0, stream>>>(h0, counts, bins, W1, b1, shA32);
    // L2: 32-node tiles (625 blocks), K=32 (24 padded), N=64
    gin_layer2<32, 8, 1, 32, 64><<<625, 256, 0, stream>>>(shA32, counts, bins, Wb2p, b2, shB64);
    // L3: 16-node tiles (1250 blocks), K=64, N=128
    gin_layer2<16, 16, 1, 64, 128><<<1250, 256, 0, stream>>>(shB64, counts, bins, Wb3, b3, shA128);
    // L4: 16-node tiles (1250 blocks), K=128, N=256
    gin_layer2<16, 16, 2, 128, 256><<<1250, 256, 0, stream>>>(shA128, counts, bins, Wb4, b4, h4b);

    attn1_cpart<<<P_PATH, 256, 0, stream>>>(h4b, path, Wih, Whh, bih, bhh, r0b, cpart_all);
    mfma_gates<<<dim3(8, 16, 3), 256, 0, stream>>>(r0b, Wihb, cpart_all, gates_all);
    attn2<<<P_PATH, 256, 0, stream>>>(h4b, path, gates_all, bih, bhh, Wg, bg, xg);
    final_mlp<<<1, 256, 0, stream>>>(xg, Wl1b, bl1, Wl2, bl2, Wl3, bl3, (float*)d_out);
}